// Round 2
// baseline (1305.757 us; speedup 1.0000x reference)
//
#include <hip/hip_runtime.h>
#include <cstdint>
#include <cstddef>

#define NN 25000
#define NE 400000
#define NFD 30
#define EFD 10
#define H 40
#define T 5
#define FO 8
#define LAYERS 2
#define TF 200          // T*F
#define BASE_W 800      // T*160
#define PSTR 52         // padded row stride for P1/P2 (52*4=208B, 16B aligned)
#define EPSV 1e-5f

// ---------- degree histogram ----------
__global__ __launch_bounds__(256) void k_deg(const int* __restrict__ dst, int* __restrict__ cnt) {
    int e = blockIdx.x * 256 + threadIdx.x;
    if (e < NE) atomicAdd(&cnt[dst[e]], 1);
}

// ---------- sum of log(cnt+1) ----------
__global__ __launch_bounds__(256) void k_avglog(const int* __restrict__ cnt, float* __restrict__ slot) {
    __shared__ float red[256];
    float s = 0.0f;
    for (int i = blockIdx.x * 256 + threadIdx.x; i < NN; i += gridDim.x * 256)
        s += logf((float)cnt[i] + 1.0f);
    red[threadIdx.x] = s; __syncthreads();
    for (int o = 128; o > 0; o >>= 1) {
        if (threadIdx.x < o) red[threadIdx.x] += red[threadIdx.x + o];
        __syncthreads();
    }
    if (threadIdx.x == 0) atomicAdd(slot, red[0]);
}

// ---------- per-node amp/att ----------
__global__ __launch_bounds__(256) void k_ampatt(const int* __restrict__ cnt, const float* __restrict__ slot,
                                                float* __restrict__ amp, float* __restrict__ att) {
    int i = blockIdx.x * 256 + threadIdx.x;
    if (i >= NN) return;
    float avg = slot[0] / (float)NN;
    float c1 = fmaxf((float)cnt[i], 1.0f);
    float lg = logf(c1 + 1.0f);
    amp[i] = lg / avg;
    att[i] = avg / lg;
}

// ---------- h0 = x @ node_w + node_b ----------
__global__ __launch_bounds__(256) void k_node_enc(const float* __restrict__ x, const float* __restrict__ w,
                                                  const float* __restrict__ b, float* __restrict__ h) {
    int id = blockIdx.x * 256 + threadIdx.x;
    if (id >= NN * H) return;
    int n = id / H, j = id - n * H;
    const float* xr = x + (size_t)n * NFD;
    float acc = b[j];
    #pragma unroll
    for (int m = 0; m < NFD; m++) acc += xr[m] * w[m * H + j];
    h[id] = acc;
}

// ---------- exclusive scan of cnt -> offsets (int4-chunked, 1 block) ----------
__global__ __launch_bounds__(1024) void k_scan(const int* __restrict__ cnt, int* __restrict__ offs) {
    __shared__ int buf[1024];
    __shared__ int runbase;
    int tid = threadIdx.x;
    if (tid == 0) runbase = 0;
    __syncthreads();
    for (int base = 0; base < NN; base += 4096) {
        int i0 = base + tid * 4;
        int4 v = make_int4(0, 0, 0, 0);
        if (i0 < NN) v = *(const int4*)(cnt + i0);   // NN % 4 == 0
        int tsum = v.x + v.y + v.z + v.w;
        buf[tid] = tsum; __syncthreads();
        for (int o = 1; o < 1024; o <<= 1) {
            int t = (tid >= o) ? buf[tid - o] : 0;
            __syncthreads();
            buf[tid] += t;
            __syncthreads();
        }
        int excl = runbase + buf[tid] - tsum;
        if (i0 < NN) {
            offs[i0]     = excl;
            offs[i0 + 1] = excl + v.x;
            offs[i0 + 2] = excl + v.x + v.y;
            offs[i0 + 3] = excl + v.x + v.y + v.z;
        }
        __syncthreads();
        if (tid == 1023) runbase += buf[1023];
        __syncthreads();
    }
    if (tid == 0) offs[NN] = runbase;
}

// ---------- scatter edges into CSR ----------
__global__ __launch_bounds__(256) void k_scatter(const int* __restrict__ src, const int* __restrict__ dst,
                                                 const int* __restrict__ offs, int* __restrict__ fill,
                                                 int* __restrict__ csr_eid, int* __restrict__ csr_src) {
    int e = blockIdx.x * 256 + threadIdx.x;
    if (e >= NE) return;
    int d = dst[e];
    int p = offs[d] + atomicAdd(&fill[d], 1);
    csr_eid[p] = e;
    csr_src[p] = src[e];
}

// ---------- G[k][j] = sum_o enc_w[k][o]*pre_w[t][80+o][f];  dvec0 = pre_b + enc_b@P3 ----------
__global__ __launch_bounds__(256) void k_w3p(const float* __restrict__ enc_w, const float* __restrict__ enc_b,
                                             const float* __restrict__ pre_w, const float* __restrict__ pre_b,
                                             float* __restrict__ G, float* __restrict__ dvec0, int layer) {
    int id = blockIdx.x * 256 + threadIdx.x;
    if (id >= H * TF) return;
    int k = id / TF, j = id - k * TF;
    int t = j / H, f = j - t * H;
    const float* ew = enc_w + (size_t)layer * H * H;
    const float* pw = pre_w + ((size_t)(layer * T + t) * 120) * H;
    float acc = 0.0f;
    #pragma unroll
    for (int o = 0; o < H; o++) acc += ew[k * H + o] * pw[(80 + o) * H + f];
    G[k * TF + j] = acc;
    if (k == 0) {
        const float* eb = enc_b + (size_t)layer * H;
        float dacc = pre_b[(size_t)(layer * T + t) * H + f];
        #pragma unroll
        for (int o = 0; o < H; o++) dacc += eb[o] * pw[(80 + o) * H + f];
        dvec0[j] = dacc;
    }
}

// ---------- W3e[m][j] = sum_k edge_w[m][k]*G[k][j];  dvecF = dvec0 + edge_b@G ----------
__global__ __launch_bounds__(256) void k_w3e(const float* __restrict__ edge_w, const float* __restrict__ edge_b,
                                             const float* __restrict__ G, const float* __restrict__ dvec0,
                                             float* __restrict__ w3e, float* __restrict__ dvecF) {
    int id = blockIdx.x * 256 + threadIdx.x;
    if (id >= EFD * TF) return;
    int m = id / TF, j = id - m * TF;
    float acc = 0.0f;
    #pragma unroll
    for (int k = 0; k < H; k++) acc += edge_w[m * H + k] * G[k * TF + j];
    w3e[id] = acc;
    if (m == 0) {
        float dacc = dvec0[j];
        #pragma unroll
        for (int k = 0; k < H; k++) dacc += edge_b[k] * G[k * TF + j];
        dvecF[j] = dacc;
    }
}

// ---------- transpose pre_w A/B parts: p1T[j][m], p2T[j][m] ----------
__global__ __launch_bounds__(256) void k_preT(const float* __restrict__ pre_w,
                                              float* __restrict__ p1T, float* __restrict__ p2T, int layer) {
    int id = blockIdx.x * 256 + threadIdx.x;
    if (id >= TF * H) return;
    int j = id / H, m = id - j * H;
    int t = j / H, f = j - t * H;
    const float* pw = pre_w + (size_t)(layer * T + t) * 120 * H;
    p1T[id] = pw[m * H + f];
    p2T[id] = pw[(H + m) * H + f];
}

// ---------- A = h@P1, B = h@P2 (flat mapping, float4 rows) ----------
__global__ __launch_bounds__(256) void k_ab(const float* __restrict__ h, const float* __restrict__ p1T,
                                            const float* __restrict__ p2T, float* __restrict__ A,
                                            float* __restrict__ B) {
    int flat = blockIdx.x * 256 + threadIdx.x;
    if (flat >= NN * TF) return;
    int n = flat / TF, j = flat - n * TF;
    const float4* hr  = (const float4*)(h + (size_t)n * H);
    const float4* w1r = (const float4*)(p1T + (size_t)j * H);
    const float4* w2r = (const float4*)(p2T + (size_t)j * H);
    float a = 0.0f, b = 0.0f;
    #pragma unroll
    for (int m4 = 0; m4 < H / 4; m4++) {
        float4 hv = hr[m4], xw = w1r[m4], yw = w2r[m4];
        a += hv.x * xw.x + hv.y * xw.y + hv.z * xw.z + hv.w * xw.w;
        b += hv.x * yw.x + hv.y * yw.y + hv.z * yw.z + hv.w * yw.w;
    }
    A[flat] = a;
    B[flat] = b;
}

// ---------- aggregation (flat mapping; C from edge_attr directly, 10 FMA) ----------
__global__ __launch_bounds__(256) void k_agg(const float* __restrict__ edge_attr, const float* __restrict__ B,
                                             const float* __restrict__ A, const float* __restrict__ w3e,
                                             const float* __restrict__ dvecF, const int* __restrict__ cnt,
                                             const int* __restrict__ offs, const int* __restrict__ csr_eid,
                                             const int* __restrict__ csr_src, float* __restrict__ base) {
    int flat = blockIdx.x * 256 + threadIdx.x;
    if (flat >= NN * TF) return;
    int n = flat / TF, j = flat - n * TF;
    float w3c[EFD];
    #pragma unroll
    for (int m = 0; m < EFD; m++) w3c[m] = w3e[m * TF + j];
    float dj = dvecF[j];
    int deg = cnt[n];
    int start = offs[n];
    float s = 0.0f, q = 0.0f, mn = 3.4e38f, mx = -3.4e38f;
    for (int r = 0; r < deg; r++) {
        int eid = csr_eid[start + r];
        int sn  = csr_src[start + r];
        const float2* ea2 = (const float2*)(edge_attr + (size_t)eid * EFD);
        float C = dj;
        #pragma unroll
        for (int m2 = 0; m2 < EFD / 2; m2++) {
            float2 ev = ea2[m2];
            C += ev.x * w3c[2 * m2] + ev.y * w3c[2 * m2 + 1];
        }
        float u = B[(size_t)sn * TF + j] + C;
        s += u; q += u * u;
        mn = fminf(mn, u); mx = fmaxf(mx, u);
    }
    float a = A[flat];
    float d = (float)deg, c1 = fmaxf(d, 1.0f);
    float mean = (d * a + s) / c1;
    float msq  = (d * a * a + 2.0f * a * s + q) / c1;
    float sd   = sqrtf(fmaxf(msq - mean * mean, 0.0f) + EPSV);
    float mnv = (deg > 0) ? (a + mn) : 0.0f;
    float mxv = (deg > 0) ? (a + mx) : 0.0f;
    int t = j / H, f = j - t * H;
    float* bb = base + (size_t)n * BASE_W + t * 160 + f;
    bb[0]   = mean;
    bb[40]  = mnv;
    bb[80]  = mxv;
    bb[120] = sd;
}

// ---------- transpose post_w: pwT[q][g] = post_w[t][g][o], q=t*8+o ----------
__global__ __launch_bounds__(256) void k_postT(const float* __restrict__ post_w, float* __restrict__ pwT, int layer) {
    int id = blockIdx.x * 256 + threadIdx.x;
    if (id >= H * 520) return;
    int q = id / 520, g = id - q * 520;
    int t = q / FO, o = q - t * FO;
    pwT[id] = post_w[((size_t)(layer * T + t) * 520 + g) * FO + o];
}

// ---------- post einsum + lin (6 nodes/block, contiguous pwT rows) ----------
__global__ __launch_bounds__(256) void k_post(const float* __restrict__ h, const float* __restrict__ base,
                                              const float* __restrict__ amp, const float* __restrict__ att,
                                              const float* __restrict__ pwT, const float* __restrict__ post_b,
                                              const float* __restrict__ lin_w, const float* __restrict__ lin_b,
                                              float* __restrict__ cbuf, int layer) {
    __shared__ float shx[6][H];
    __shared__ float sout[6][H];
    int local = threadIdx.x;
    int nl = local / H, q = local - nl * H;
    int n = blockIdx.x * 6 + nl;
    bool act = (nl < 6) && (n < NN);
    if (act) shx[nl][q] = h[(size_t)n * H + q];
    __syncthreads();
    if (act) {
        int t = q / FO, o = q - t * FO;
        const float4* pw4 = (const float4*)(pwT + (size_t)q * 520);
        float am = amp[n], at = att[n];
        float acc = post_b[(size_t)(layer * T + t) * FO + o];
        const float4* sx4 = (const float4*)(&shx[nl][0]);
        #pragma unroll
        for (int g4 = 0; g4 < 10; g4++) {
            float4 xv = sx4[g4];
            float4 wv = pw4[g4];
            acc += xv.x * wv.x + xv.y * wv.y + xv.z * wv.z + xv.w * wv.w;
        }
        const float4* br4 = (const float4*)(base + (size_t)n * BASE_W + t * 160);
        #pragma unroll
        for (int g4 = 0; g4 < 40; g4++) {
            float4 bv = br4[g4];
            float4 wa = pw4[10 + g4];
            float4 wb = pw4[50 + g4];
            float4 wc = pw4[90 + g4];
            acc += bv.x * (wa.x + am * wb.x + at * wc.x);
            acc += bv.y * (wa.y + am * wb.y + at * wc.y);
            acc += bv.z * (wa.z + am * wb.z + at * wc.z);
            acc += bv.w * (wa.w + am * wb.w + at * wc.w);
        }
        sout[nl][q] = acc;
    }
    __syncthreads();
    if (act) {
        const float* lw = lin_w + (size_t)layer * H * H;
        float acc = lin_b[(size_t)layer * H + q];
        #pragma unroll
        for (int k = 0; k < H; k++) acc += sout[nl][k] * lw[k * H + q];
        cbuf[(size_t)n * H + q] = acc;
    }
}

// ---------- BN stats ----------
__global__ __launch_bounds__(320) void k_bnstats(const float* __restrict__ cbuf,
                                                 float* __restrict__ bnsum, float* __restrict__ bnsq) {
    __shared__ float ls[320], lq[320];
    int tid = threadIdx.x;
    int stride = gridDim.x * 320;
    float s = 0.0f, q = 0.0f;
    for (int idx = blockIdx.x * 320 + tid; idx < NN * H; idx += stride) {
        float v = cbuf[idx];
        s += v; q += v * v;
    }
    ls[tid] = s; lq[tid] = q;
    __syncthreads();
    if (tid < H) {
        float ss = 0.0f, qq = 0.0f;
        #pragma unroll
        for (int r = 0; r < 8; r++) { ss += ls[r * H + tid]; qq += lq[r * H + tid]; }
        atomicAdd(&bnsum[tid], ss);
        atomicAdd(&bnsq[tid], qq);
    }
}

// ---------- BN apply + residual ----------
__global__ __launch_bounds__(256) void k_bnapply(const float* __restrict__ cbuf, const float* __restrict__ bnsum,
                                                 const float* __restrict__ bnsq, const float* __restrict__ bn_g,
                                                 const float* __restrict__ bn_b, float* __restrict__ h, int layer) {
    int id = blockIdx.x * 256 + threadIdx.x;
    if (id >= NN * H) return;
    int j = id % H;
    float mu = bnsum[j] / (float)NN;
    float var = bnsq[j] / (float)NN - mu * mu;
    float inv = rsqrtf(var + EPSV);
    float cv = (cbuf[id] - mu) * inv * bn_g[(size_t)layer * H + j] + bn_b[(size_t)layer * H + j];
    h[id] = (h[id] + fmaxf(cv, 0.0f)) * 0.5f;
}

// ---------- W1e = edge_w @ w1[80:120];  b1e = b1 + edge_b @ w1[80:120] ----------
__global__ __launch_bounds__(256) void k_w1e(const float* __restrict__ edge_w, const float* __restrict__ edge_b,
                                             const float* __restrict__ w1, const float* __restrict__ b1,
                                             float* __restrict__ W1e, float* __restrict__ b1e) {
    int id = blockIdx.x * 256 + threadIdx.x;
    if (id >= EFD * 50) return;
    int m = id / 50, o = id - m * 50;
    float acc = 0.0f;
    #pragma unroll
    for (int k = 0; k < H; k++) acc += edge_w[m * H + k] * w1[(80 + k) * 50 + o];
    W1e[id] = acc;
    if (m == 0) {
        float bacc = b1[o];
        #pragma unroll
        for (int k = 0; k < H; k++) bacc += edge_b[k] * w1[(80 + k) * 50 + o];
        b1e[o] = bacc;
    }
}

// ---------- P1 = relu(h)@w1[0:40], P2 = relu(h)@w1[40:80]  (padded stride 52) ----------
__global__ __launch_bounds__(256) void k_p12(const float* __restrict__ h, const float* __restrict__ w1,
                                             float* __restrict__ P1, float* __restrict__ P2) {
    int id = blockIdx.x * 256 + threadIdx.x;
    if (id >= NN * 50) return;
    int n = id / 50, o = id - n * 50;
    const float* hr = h + (size_t)n * H;
    float a1 = 0.0f, a2 = 0.0f;
    #pragma unroll
    for (int f = 0; f < H; f++) {
        float v = fmaxf(hr[f], 0.0f);
        a1 += v * w1[f * 50 + o];
        a2 += v * w1[(H + f) * 50 + o];
    }
    P1[(size_t)n * PSTR + o] = a1;
    P2[(size_t)n * PSTR + o] = a2;
}

// ---------- final edge MLP (folded first layer) ----------
__global__ __launch_bounds__(256) void k_mlp(const float* __restrict__ edge_attr, const float* __restrict__ P1,
                                             const float* __restrict__ P2, const int* __restrict__ srcp,
                                             const int* __restrict__ dstp, const float* __restrict__ W1e,
                                             const float* __restrict__ b1e, const float* __restrict__ w2,
                                             const float* __restrict__ b2, const float* __restrict__ w3,
                                             const float* __restrict__ b3, float* __restrict__ out) {
    int e = blockIdx.x * 256 + threadIdx.x;
    if (e >= NE) return;
    int s = srcp[e], d = dstp[e];
    float ea[EFD];
    const float2* ea2 = (const float2*)(edge_attr + (size_t)e * EFD);
    #pragma unroll
    for (int m2 = 0; m2 < EFD / 2; m2++) {
        float2 v = ea2[m2];
        ea[2 * m2] = v.x; ea[2 * m2 + 1] = v.y;
    }
    float z1[52];
    const float4* p1r = (const float4*)(P1 + (size_t)s * PSTR);
    const float4* p2r = (const float4*)(P2 + (size_t)d * PSTR);
    #pragma unroll
    for (int i = 0; i < 13; i++) {
        float4 a = p1r[i], b = p2r[i];
        z1[4 * i]     = a.x + b.x;
        z1[4 * i + 1] = a.y + b.y;
        z1[4 * i + 2] = a.z + b.z;
        z1[4 * i + 3] = a.w + b.w;
    }
    #pragma unroll
    for (int o = 0; o < 50; o++) z1[o] += b1e[o];
    #pragma unroll
    for (int m = 0; m < EFD; m++) {
        float v = ea[m];
        #pragma unroll
        for (int o = 0; o < 50; o++) z1[o] += v * W1e[m * 50 + o];
    }
    float z2[25];
    #pragma unroll
    for (int o = 0; o < 25; o++) z2[o] = b2[o];
    #pragma unroll
    for (int k = 0; k < 50; k++) {
        float v = fmaxf(z1[k], 0.0f);
        #pragma unroll
        for (int o = 0; o < 25; o++) z2[o] += v * w2[k * 25 + o];
    }
    float o0 = b3[0], o1 = b3[1];
    #pragma unroll
    for (int k = 0; k < 25; k++) {
        float v = fmaxf(z2[k], 0.0f);
        o0 += v * w3[k * 2];
        o1 += v * w3[k * 2 + 1];
    }
    out[(size_t)e * 2]     = o0;
    out[(size_t)e * 2 + 1] = o1;
}

extern "C" void kernel_launch(void* const* d_in, const int* in_sizes, int n_in,
                              void* d_out, int out_size, void* d_ws, size_t ws_size,
                              hipStream_t stream) {
    const float* x         = (const float*)d_in[0];
    const float* edge_attr = (const float*)d_in[1];
    const int*   eidx      = (const int*)  d_in[2];
    const float* node_w    = (const float*)d_in[3];
    const float* node_b    = (const float*)d_in[4];
    const float* edge_w    = (const float*)d_in[5];
    const float* edge_b    = (const float*)d_in[6];
    const float* enc_w     = (const float*)d_in[7];
    const float* enc_b     = (const float*)d_in[8];
    const float* pre_w     = (const float*)d_in[9];
    const float* pre_b     = (const float*)d_in[10];
    const float* post_w    = (const float*)d_in[11];
    const float* post_b    = (const float*)d_in[12];
    const float* lin_w     = (const float*)d_in[13];
    const float* lin_b     = (const float*)d_in[14];
    const float* bn_g      = (const float*)d_in[15];
    const float* bn_b      = (const float*)d_in[16];
    const float* w1 = (const float*)d_in[17];
    const float* b1 = (const float*)d_in[18];
    const float* w2 = (const float*)d_in[19];
    const float* b2 = (const float*)d_in[20];
    const float* w3 = (const float*)d_in[21];
    const float* b3 = (const float*)d_in[22];
    const int* srcp = eidx;
    const int* dstp = eidx + NE;
    float* out = (float*)d_out;

    char* ws = (char*)d_ws;
    size_t off = 0;
    auto alloc = [&](size_t bytes) -> char* {
        char* p = ws + off;
        off += (bytes + 255) & ~(size_t)255;
        return p;
    };
    float* h     = (float*)alloc((size_t)NN * H * 4);
    float* Abuf  = (float*)alloc((size_t)NN * TF * 4);
    float* Bbuf  = (float*)alloc((size_t)NN * TF * 4);
    float* base  = (float*)alloc((size_t)NN * BASE_W * 4);
    float* cbuf  = (float*)alloc((size_t)NN * H * 4);
    float* Gbuf  = (float*)alloc((size_t)H * TF * 4);
    float* dvec0 = (float*)alloc((size_t)TF * 4);
    float* dvecF = (float*)alloc((size_t)TF * 4);
    float* w3e   = (float*)alloc((size_t)EFD * TF * 4);
    float* p1T   = (float*)alloc((size_t)TF * H * 4);
    float* p2T   = (float*)alloc((size_t)TF * H * 4);
    float* pwT   = (float*)alloc((size_t)H * 520 * 4);
    float* P1    = (float*)alloc((size_t)NN * PSTR * 4);
    float* P2    = (float*)alloc((size_t)NN * PSTR * 4);
    float* W1e   = (float*)alloc((size_t)EFD * 50 * 4);
    float* b1e   = (float*)alloc((size_t)64 * 4);
    float* amp   = (float*)alloc((size_t)NN * 4);
    float* att   = (float*)alloc((size_t)NN * 4);
    float* avgs  = (float*)alloc(256);
    float* bnz   = (float*)alloc(512);   // [0:40) sum, [40:80) sumsq
    int* cnt_i   = (int*)alloc((size_t)NN * 4);
    int* offs    = (int*)alloc((size_t)(NN + 1) * 4);
    int* fill    = (int*)alloc((size_t)NN * 4);
    int* csr_eid = (int*)alloc((size_t)NE * 4);
    int* csr_src = (int*)alloc((size_t)NE * 4);
    if (off > ws_size) return;

    hipMemsetAsync(cnt_i, 0, (size_t)NN * 4, stream);
    hipMemsetAsync(fill, 0, (size_t)NN * 4, stream);
    hipMemsetAsync(avgs, 0, 4, stream);

    k_deg<<<(NE + 255) / 256, 256, 0, stream>>>(dstp, cnt_i);
    k_avglog<<<64, 256, 0, stream>>>(cnt_i, avgs);
    k_ampatt<<<(NN + 255) / 256, 256, 0, stream>>>(cnt_i, avgs, amp, att);
    k_node_enc<<<(NN * H + 255) / 256, 256, 0, stream>>>(x, node_w, node_b, h);
    k_scan<<<1, 1024, 0, stream>>>(cnt_i, offs);
    k_scatter<<<(NE + 255) / 256, 256, 0, stream>>>(srcp, dstp, offs, fill, csr_eid, csr_src);

    for (int layer = 0; layer < LAYERS; layer++) {
        k_w3p<<<(H * TF + 255) / 256, 256, 0, stream>>>(enc_w, enc_b, pre_w, pre_b, Gbuf, dvec0, layer);
        k_w3e<<<(EFD * TF + 255) / 256, 256, 0, stream>>>(edge_w, edge_b, Gbuf, dvec0, w3e, dvecF);
        k_preT<<<(TF * H + 255) / 256, 256, 0, stream>>>(pre_w, p1T, p2T, layer);
        k_ab<<<(NN * TF + 255) / 256, 256, 0, stream>>>(h, p1T, p2T, Abuf, Bbuf);
        k_agg<<<(NN * TF + 255) / 256, 256, 0, stream>>>(edge_attr, Bbuf, Abuf, w3e, dvecF,
                                                         cnt_i, offs, csr_eid, csr_src, base);
        k_postT<<<(H * 520 + 255) / 256, 256, 0, stream>>>(post_w, pwT, layer);
        k_post<<<(NN + 5) / 6, 256, 0, stream>>>(h, base, amp, att, pwT, post_b, lin_w, lin_b, cbuf, layer);
        hipMemsetAsync(bnz, 0, 320, stream);
        k_bnstats<<<64, 320, 0, stream>>>(cbuf, bnz, bnz + 40);
        k_bnapply<<<(NN * H + 255) / 256, 256, 0, stream>>>(cbuf, bnz, bnz + 40, bn_g, bn_b, h, layer);
    }
    k_w1e<<<(EFD * 50 + 255) / 256, 256, 0, stream>>>(edge_w, edge_b, w1, b1, W1e, b1e);
    k_p12<<<(NN * 50 + 255) / 256, 256, 0, stream>>>(h, w1, P1, P2);
    k_mlp<<<(NE + 255) / 256, 256, 0, stream>>>(edge_attr, P1, P2, srcp, dstp, W1e, b1e, w2, b2, w3, b3, out);
}

// Round 3
// 927.029 us; speedup vs baseline: 1.4085x; 1.4085x over previous
//
#include <hip/hip_runtime.h>
#include <cstdint>
#include <cstddef>

#define NN 25000
#define NE 400000
#define NFD 30
#define EFD 10
#define H 40
#define T 5
#define FO 8
#define LAYERS 2
#define TF 200          // T*F
#define BASE_W 800      // T*160
#define PSTR 52         // padded row stride for P1/P2
#define CHUNK 128       // edges staged in LDS per round in k_agg
#define WS_PAD 532      // padded LDS row stride (floats) for post weights
#define EPSV 1e-5f

// ---------- degree histogram ----------
__global__ __launch_bounds__(256) void k_deg(const int* __restrict__ dst, int* __restrict__ cnt) {
    int e = blockIdx.x * 256 + threadIdx.x;
    if (e < NE) atomicAdd(&cnt[dst[e]], 1);
}

// ---------- sum of log(cnt+1) ----------
__global__ __launch_bounds__(256) void k_avglog(const int* __restrict__ cnt, float* __restrict__ slot) {
    __shared__ float red[256];
    float s = 0.0f;
    for (int i = blockIdx.x * 256 + threadIdx.x; i < NN; i += gridDim.x * 256)
        s += logf((float)cnt[i] + 1.0f);
    red[threadIdx.x] = s; __syncthreads();
    for (int o = 128; o > 0; o >>= 1) {
        if (threadIdx.x < o) red[threadIdx.x] += red[threadIdx.x + o];
        __syncthreads();
    }
    if (threadIdx.x == 0) atomicAdd(slot, red[0]);
}

// ---------- per-node amp/att ----------
__global__ __launch_bounds__(256) void k_ampatt(const int* __restrict__ cnt, const float* __restrict__ slot,
                                                float* __restrict__ amp, float* __restrict__ att) {
    int i = blockIdx.x * 256 + threadIdx.x;
    if (i >= NN) return;
    float avg = slot[0] / (float)NN;
    float c1 = fmaxf((float)cnt[i], 1.0f);
    float lg = logf(c1 + 1.0f);
    amp[i] = lg / avg;
    att[i] = avg / lg;
}

// ---------- h0 = x @ node_w + node_b ----------
__global__ __launch_bounds__(256) void k_node_enc(const float* __restrict__ x, const float* __restrict__ w,
                                                  const float* __restrict__ b, float* __restrict__ h) {
    int id = blockIdx.x * 256 + threadIdx.x;
    if (id >= NN * H) return;
    int n = id / H, j = id - n * H;
    const float* xr = x + (size_t)n * NFD;
    float acc = b[j];
    #pragma unroll
    for (int m = 0; m < NFD; m++) acc += xr[m] * w[m * H + j];
    h[id] = acc;
}

// ---------- exclusive scan of cnt -> offsets (int4-chunked, 1 block) ----------
__global__ __launch_bounds__(1024) void k_scan(const int* __restrict__ cnt, int* __restrict__ offs) {
    __shared__ int buf[1024];
    __shared__ int runbase;
    int tid = threadIdx.x;
    if (tid == 0) runbase = 0;
    __syncthreads();
    for (int base = 0; base < NN; base += 4096) {
        int i0 = base + tid * 4;
        int4 v = make_int4(0, 0, 0, 0);
        if (i0 < NN) v = *(const int4*)(cnt + i0);   // NN % 4 == 0
        int tsum = v.x + v.y + v.z + v.w;
        buf[tid] = tsum; __syncthreads();
        for (int o = 1; o < 1024; o <<= 1) {
            int t = (tid >= o) ? buf[tid - o] : 0;
            __syncthreads();
            buf[tid] += t;
            __syncthreads();
        }
        int excl = runbase + buf[tid] - tsum;
        if (i0 < NN) {
            offs[i0]     = excl;
            offs[i0 + 1] = excl + v.x;
            offs[i0 + 2] = excl + v.x + v.y;
            offs[i0 + 3] = excl + v.x + v.y + v.z;
        }
        __syncthreads();
        if (tid == 1023) runbase += buf[1023];
        __syncthreads();
    }
    if (tid == 0) offs[NN] = runbase;
}

// ---------- scatter edges into CSR order: ea_csr[p] = [ea0..ea9, srcbits, pad] ----------
__global__ __launch_bounds__(256) void k_scatter(const int* __restrict__ src, const int* __restrict__ dst,
                                                 const float* __restrict__ edge_attr,
                                                 const int* __restrict__ offs, int* __restrict__ fill,
                                                 float* __restrict__ ea_csr) {
    int e = blockIdx.x * 256 + threadIdx.x;
    if (e >= NE) return;
    int d = dst[e];
    int p = offs[d] + atomicAdd(&fill[d], 1);
    const float2* ear = (const float2*)(edge_attr + (size_t)e * EFD);
    float* o = ea_csr + (size_t)p * 12;
    #pragma unroll
    for (int m2 = 0; m2 < 5; m2++) {
        float2 v = ear[m2];
        o[2 * m2] = v.x; o[2 * m2 + 1] = v.y;
    }
    o[10] = __int_as_float(src[e]);
    o[11] = 0.0f;
}

// ---------- per-layer prep: W3e/dvecF (fold enc+edge encoders into edge_attr weights) + p1T/p2T ----------
__global__ __launch_bounds__(256) void k_prep1(const float* __restrict__ enc_w, const float* __restrict__ enc_b,
                                               const float* __restrict__ edge_w, const float* __restrict__ edge_b,
                                               const float* __restrict__ pre_w, const float* __restrict__ pre_b,
                                               float* __restrict__ W3e, float* __restrict__ dvecF,
                                               float* __restrict__ p1T, float* __restrict__ p2T, int layer) {
    int id = blockIdx.x * 256 + threadIdx.x;
    if (id < EFD * TF) {
        int m = id / TF, j = id - m * TF;
        int t = j / H, f = j - t * H;
        const float* ew = enc_w + (size_t)layer * H * H;
        const float* pw = pre_w + (size_t)(layer * T + t) * 120 * H;
        float acc = 0.0f;
        for (int k = 0; k < H; k++) {
            float wk = edge_w[m * H + k];
            float g = 0.0f;
            #pragma unroll
            for (int o = 0; o < H; o++) g += ew[k * H + o] * pw[(80 + o) * H + f];
            acc += wk * g;
        }
        W3e[m * TF + j] = acc;
        if (m == 0) {
            const float* eb = enc_b + (size_t)layer * H;
            float dacc = pre_b[(size_t)(layer * T + t) * H + f];
            for (int o = 0; o < H; o++) {
                float ebe = eb[o];
                #pragma unroll
                for (int k = 0; k < H; k++) ebe += edge_b[k] * ew[k * H + o];
                dacc += ebe * pw[(80 + o) * H + f];
            }
            dvecF[j] = dacc;
        }
    } else if (id < EFD * TF + TF * H) {
        int id2 = id - EFD * TF;
        int j = id2 / H, m = id2 - j * H;
        int t = j / H, f = j - t * H;
        const float* pw = pre_w + (size_t)(layer * T + t) * 120 * H;
        p1T[id2] = pw[m * H + f];
        p2T[id2] = pw[(H + m) * H + f];
    }
}

// ---------- A = h@P1, B = h@P2 (flat mapping, float4 rows) ----------
__global__ __launch_bounds__(256) void k_ab(const float* __restrict__ h, const float* __restrict__ p1T,
                                            const float* __restrict__ p2T, float* __restrict__ A,
                                            float* __restrict__ B) {
    int flat = blockIdx.x * 256 + threadIdx.x;
    if (flat >= NN * TF) return;
    int n = flat / TF, j = flat - n * TF;
    const float4* hr  = (const float4*)(h + (size_t)n * H);
    const float4* w1r = (const float4*)(p1T + (size_t)j * H);
    const float4* w2r = (const float4*)(p2T + (size_t)j * H);
    float a = 0.0f, b = 0.0f;
    #pragma unroll
    for (int m4 = 0; m4 < H / 4; m4++) {
        float4 hv = hr[m4], xw = w1r[m4], yw = w2r[m4];
        a += hv.x * xw.x + hv.y * xw.y + hv.z * xw.z + hv.w * xw.w;
        b += hv.x * yw.x + hv.y * yw.y + hv.z * yw.z + hv.w * yw.w;
    }
    A[flat] = a;
    B[flat] = b;
}

// ---------- aggregation: block per node, LDS-staged edges, 1 global load per edge-iter ----------
__global__ __launch_bounds__(256) void k_agg(const float* __restrict__ ea_csr, const float* __restrict__ B,
                                             const float* __restrict__ A, const float* __restrict__ w3e,
                                             const float* __restrict__ dvecF, const int* __restrict__ cnt,
                                             const int* __restrict__ offs, float* __restrict__ base) {
    __shared__ float4 sea4[CHUNK * 3];
    int n = blockIdx.x;
    int tid = threadIdx.x;
    int j = tid;
    int deg = cnt[n];
    int start = offs[n];
    float w3c[EFD];
    float dj = 0.0f, a = 0.0f;
    if (j < TF) {
        #pragma unroll
        for (int m = 0; m < EFD; m++) w3c[m] = w3e[m * TF + j];
        dj = dvecF[j];
        a = A[(size_t)n * TF + j];
    }
    float s = 0.0f, q = 0.0f, mn = 3.4e38f, mx = -3.4e38f;
    int nchunks = (deg + CHUNK - 1) / CHUNK;
    for (int c = 0; c < nchunks; c++) {
        int count = deg - c * CHUNK;
        if (count > CHUNK) count = CHUNK;
        const float4* gsrc = (const float4*)(ea_csr + (size_t)(start + c * CHUNK) * 12);
        int nf4 = count * 3;
        for (int i = tid; i < nf4; i += 256) sea4[i] = gsrc[i];
        __syncthreads();
        if (j < TF) {
            int r = 0;
            for (; r + 2 <= count; r += 2) {
                float4 qa0 = sea4[r * 3],     qb0 = sea4[r * 3 + 1], qc0 = sea4[r * 3 + 2];
                float4 qa1 = sea4[r * 3 + 3], qb1 = sea4[r * 3 + 4], qc1 = sea4[r * 3 + 5];
                int sn0 = __float_as_int(qc0.z);
                int sn1 = __float_as_int(qc1.z);
                float b0 = B[(size_t)sn0 * TF + j];
                float b1 = B[(size_t)sn1 * TF + j];
                float C0 = dj + qa0.x * w3c[0] + qa0.y * w3c[1] + qa0.z * w3c[2] + qa0.w * w3c[3]
                              + qb0.x * w3c[4] + qb0.y * w3c[5] + qb0.z * w3c[6] + qb0.w * w3c[7]
                              + qc0.x * w3c[8] + qc0.y * w3c[9];
                float C1 = dj + qa1.x * w3c[0] + qa1.y * w3c[1] + qa1.z * w3c[2] + qa1.w * w3c[3]
                              + qb1.x * w3c[4] + qb1.y * w3c[5] + qb1.z * w3c[6] + qb1.w * w3c[7]
                              + qc1.x * w3c[8] + qc1.y * w3c[9];
                float u0 = b0 + C0;
                float u1 = b1 + C1;
                s += u0; q += u0 * u0; mn = fminf(mn, u0); mx = fmaxf(mx, u0);
                s += u1; q += u1 * u1; mn = fminf(mn, u1); mx = fmaxf(mx, u1);
            }
            if (r < count) {
                float4 qa = sea4[r * 3], qb = sea4[r * 3 + 1], qc = sea4[r * 3 + 2];
                int sn = __float_as_int(qc.z);
                float b0 = B[(size_t)sn * TF + j];
                float C = dj + qa.x * w3c[0] + qa.y * w3c[1] + qa.z * w3c[2] + qa.w * w3c[3]
                             + qb.x * w3c[4] + qb.y * w3c[5] + qb.z * w3c[6] + qb.w * w3c[7]
                             + qc.x * w3c[8] + qc.y * w3c[9];
                float u = b0 + C;
                s += u; q += u * u; mn = fminf(mn, u); mx = fmaxf(mx, u);
            }
        }
        __syncthreads();
    }
    if (j < TF) {
        float d = (float)deg, c1 = fmaxf(d, 1.0f);
        float mean = (d * a + s) / c1;
        float msq  = (d * a * a + 2.0f * a * s + q) / c1;
        float sd   = sqrtf(fmaxf(msq - mean * mean, 0.0f) + EPSV);
        float mnv = (deg > 0) ? (a + mn) : 0.0f;
        float mxv = (deg > 0) ? (a + mx) : 0.0f;
        int t = j / H, f = j - t * H;
        float* bb = base + (size_t)n * BASE_W + t * 160 + f;
        bb[0]   = mean;
        bb[40]  = mnv;
        bb[80]  = mxv;
        bb[120] = sd;
    }
}

// ---------- post einsum, t-split: block = 32 nodes x 8 outputs, weight slice in LDS ----------
__global__ __launch_bounds__(256) void k_post(const float* __restrict__ h, const float* __restrict__ base,
                                              const float* __restrict__ amp, const float* __restrict__ att,
                                              const float* __restrict__ post_w, const float* __restrict__ post_b,
                                              float* __restrict__ cpre, int layer) {
    __shared__ float ws[FO * WS_PAD];
    int tid = threadIdx.x;
    int t = blockIdx.y;
    const float* pwsrc = post_w + (size_t)(layer * T + t) * 520 * FO;
    for (int i = tid; i < 520 * FO; i += 256) {
        int g = i >> 3, o = i & 7;
        ws[o * WS_PAD + g] = pwsrc[i];
    }
    __syncthreads();
    int nl = tid >> 3, o = tid & 7;
    int n = blockIdx.x * 32 + nl;
    if (n >= NN) return;
    const float* wrow = ws + o * WS_PAD;
    float am = amp[n], at = att[n];
    float acc = post_b[(size_t)(layer * T + t) * FO + o];
    const float4* hx = (const float4*)(h + (size_t)n * H);
    #pragma unroll
    for (int g4 = 0; g4 < 10; g4++) {
        float4 xv = hx[g4];
        float4 wv = *(const float4*)(wrow + g4 * 4);
        acc += xv.x * wv.x + xv.y * wv.y + xv.z * wv.z + xv.w * wv.w;
    }
    const float4* br = (const float4*)(base + (size_t)n * BASE_W + t * 160);
    #pragma unroll
    for (int g4 = 0; g4 < 40; g4++) {
        float4 bv = br[g4];
        float4 wa = *(const float4*)(wrow + 40 + g4 * 4);
        float4 wb = *(const float4*)(wrow + 200 + g4 * 4);
        float4 wc = *(const float4*)(wrow + 360 + g4 * 4);
        acc += bv.x * (wa.x + am * wb.x + at * wc.x);
        acc += bv.y * (wa.y + am * wb.y + at * wc.y);
        acc += bv.z * (wa.z + am * wb.z + at * wc.z);
        acc += bv.w * (wa.w + am * wb.w + at * wc.w);
    }
    cpre[(size_t)n * H + t * FO + o] = acc;
}

// ---------- lin: cbuf = cpre @ lin_w + lin_b ----------
__global__ __launch_bounds__(256) void k_lin(const float* __restrict__ cpre, const float* __restrict__ lin_w,
                                             const float* __restrict__ lin_b, float* __restrict__ cbuf, int layer) {
    int id = blockIdx.x * 256 + threadIdx.x;
    if (id >= NN * H) return;
    int n = id / H, q = id - n * H;
    const float* cr = cpre + (size_t)n * H;
    const float* lw = lin_w + (size_t)layer * H * H;
    float acc = lin_b[(size_t)layer * H + q];
    #pragma unroll
    for (int k = 0; k < H; k++) acc += cr[k] * lw[k * H + q];
    cbuf[id] = acc;
}

// ---------- BN stats ----------
__global__ __launch_bounds__(320) void k_bnstats(const float* __restrict__ cbuf,
                                                 float* __restrict__ bnsum, float* __restrict__ bnsq) {
    __shared__ float ls[320], lq[320];
    int tid = threadIdx.x;
    int stride = gridDim.x * 320;
    float s = 0.0f, q = 0.0f;
    for (int idx = blockIdx.x * 320 + tid; idx < NN * H; idx += stride) {
        float v = cbuf[idx];
        s += v; q += v * v;
    }
    ls[tid] = s; lq[tid] = q;
    __syncthreads();
    if (tid < H) {
        float ss = 0.0f, qq = 0.0f;
        #pragma unroll
        for (int r = 0; r < 8; r++) { ss += ls[r * H + tid]; qq += lq[r * H + tid]; }
        atomicAdd(&bnsum[tid], ss);
        atomicAdd(&bnsq[tid], qq);
    }
}

// ---------- BN apply + residual ----------
__global__ __launch_bounds__(256) void k_bnapply(const float* __restrict__ cbuf, const float* __restrict__ bnsum,
                                                 const float* __restrict__ bnsq, const float* __restrict__ bn_g,
                                                 const float* __restrict__ bn_b, float* __restrict__ h, int layer) {
    int id = blockIdx.x * 256 + threadIdx.x;
    if (id >= NN * H) return;
    int j = id % H;
    float mu = bnsum[j] / (float)NN;
    float var = bnsq[j] / (float)NN - mu * mu;
    float inv = rsqrtf(var + EPSV);
    float cv = (cbuf[id] - mu) * inv * bn_g[(size_t)layer * H + j] + bn_b[(size_t)layer * H + j];
    h[id] = (h[id] + fmaxf(cv, 0.0f)) * 0.5f;
}

// ---------- final prep: W1e/b1e fold + P1/P2 node partials ----------
__global__ __launch_bounds__(256) void k_prep2(const float* __restrict__ edge_w, const float* __restrict__ edge_b,
                                               const float* __restrict__ w1, const float* __restrict__ b1,
                                               const float* __restrict__ h,
                                               float* __restrict__ W1e, float* __restrict__ b1e,
                                               float* __restrict__ P1, float* __restrict__ P2) {
    int id = blockIdx.x * 256 + threadIdx.x;
    if (id < EFD * 50) {
        int m = id / 50, o = id - m * 50;
        float acc = 0.0f;
        #pragma unroll
        for (int k = 0; k < H; k++) acc += edge_w[m * H + k] * w1[(80 + k) * 50 + o];
        W1e[m * 52 + o] = acc;
        if (m == 0) {
            float bacc = b1[o];
            #pragma unroll
            for (int k = 0; k < H; k++) bacc += edge_b[k] * w1[(80 + k) * 50 + o];
            b1e[o] = bacc;
        }
        if (o >= 48) { W1e[m * 52 + o + 2] = 0.0f; if (m == 0) b1e[o + 2] = 0.0f; }
    } else if (id < EFD * 50 + NN * 50) {
        int id2 = id - EFD * 50;
        int n = id2 / 50, o = id2 - n * 50;
        const float* hr = h + (size_t)n * H;
        float a1 = 0.0f, a2 = 0.0f;
        #pragma unroll
        for (int f = 0; f < H; f++) {
            float v = fmaxf(hr[f], 0.0f);
            a1 += v * w1[f * 50 + o];
            a2 += v * w1[(H + f) * 50 + o];
        }
        P1[(size_t)n * PSTR + o] = a1;
        P2[(size_t)n * PSTR + o] = a2;
    }
}

// ---------- final edge MLP, weights staged in LDS ----------
__global__ __launch_bounds__(256) void k_mlp(const float* __restrict__ edge_attr, const float* __restrict__ P1,
                                             const float* __restrict__ P2, const int* __restrict__ srcp,
                                             const int* __restrict__ dstp, const float* __restrict__ W1e,
                                             const float* __restrict__ b1e, const float* __restrict__ w2,
                                             const float* __restrict__ b2, const float* __restrict__ w3,
                                             const float* __restrict__ b3, float* __restrict__ out) {
    __shared__ float sW1[EFD * 52];   // padded to 52
    __shared__ float sb1[52];
    __shared__ float sw2[50 * 28];    // padded to 28
    __shared__ float sw3[50];
    __shared__ float sb2[25];
    __shared__ float sb3[2];
    int tid = threadIdx.x;
    for (int i = tid; i < EFD * 52; i += 256) sW1[i] = W1e[i];
    for (int i = tid; i < 52; i += 256) sb1[i] = b1e[i];
    for (int i = tid; i < 50 * 28; i += 256) {
        int k = i / 28, o = i - k * 28;
        sw2[i] = (o < 25) ? w2[k * 25 + o] : 0.0f;
    }
    for (int i = tid; i < 50; i += 256) sw3[i] = w3[i];
    for (int i = tid; i < 25; i += 256) sb2[i] = b2[i];
    if (tid < 2) sb3[tid] = b3[tid];
    __syncthreads();

    int e = blockIdx.x * 256 + tid;
    if (e >= NE) return;
    int s = srcp[e], d = dstp[e];
    float z1[52];
    const float4* p1r = (const float4*)(P1 + (size_t)s * PSTR);
    const float4* p2r = (const float4*)(P2 + (size_t)d * PSTR);
    #pragma unroll
    for (int i = 0; i < 13; i++) {
        float4 a = p1r[i], b = p2r[i];
        z1[4 * i]     = a.x + b.x + sb1[4 * i];
        z1[4 * i + 1] = a.y + b.y + sb1[4 * i + 1];
        z1[4 * i + 2] = a.z + b.z + sb1[4 * i + 2];
        z1[4 * i + 3] = a.w + b.w + sb1[4 * i + 3];
    }
    const float2* ea2 = (const float2*)(edge_attr + (size_t)e * EFD);
    #pragma unroll
    for (int m2 = 0; m2 < 5; m2++) {
        float2 v = ea2[m2];
        const float* wr0 = sW1 + (2 * m2) * 52;
        const float* wr1 = sW1 + (2 * m2 + 1) * 52;
        #pragma unroll
        for (int i = 0; i < 13; i++) {
            float4 w0 = *(const float4*)(wr0 + 4 * i);
            float4 w1v = *(const float4*)(wr1 + 4 * i);
            z1[4 * i]     += v.x * w0.x + v.y * w1v.x;
            z1[4 * i + 1] += v.x * w0.y + v.y * w1v.y;
            z1[4 * i + 2] += v.x * w0.z + v.y * w1v.z;
            z1[4 * i + 3] += v.x * w0.w + v.y * w1v.w;
        }
    }
    float z2[28];
    #pragma unroll
    for (int o = 0; o < 25; o++) z2[o] = sb2[o];
    z2[25] = z2[26] = z2[27] = 0.0f;
    #pragma unroll
    for (int k = 0; k < 50; k++) {
        float v = fmaxf(z1[k], 0.0f);
        const float* wr = sw2 + k * 28;
        #pragma unroll
        for (int i = 0; i < 7; i++) {
            float4 w = *(const float4*)(wr + 4 * i);
            z2[4 * i]     += v * w.x;
            z2[4 * i + 1] += v * w.y;
            z2[4 * i + 2] += v * w.z;
            z2[4 * i + 3] += v * w.w;
        }
    }
    float o0 = sb3[0], o1 = sb3[1];
    #pragma unroll
    for (int k = 0; k < 25; k++) {
        float v = fmaxf(z2[k], 0.0f);
        o0 += v * sw3[k * 2];
        o1 += v * sw3[k * 2 + 1];
    }
    out[(size_t)e * 2]     = o0;
    out[(size_t)e * 2 + 1] = o1;
}

extern "C" void kernel_launch(void* const* d_in, const int* in_sizes, int n_in,
                              void* d_out, int out_size, void* d_ws, size_t ws_size,
                              hipStream_t stream) {
    const float* x         = (const float*)d_in[0];
    const float* edge_attr = (const float*)d_in[1];
    const int*   eidx      = (const int*)  d_in[2];
    const float* node_w    = (const float*)d_in[3];
    const float* node_b    = (const float*)d_in[4];
    const float* edge_w    = (const float*)d_in[5];
    const float* edge_b    = (const float*)d_in[6];
    const float* enc_w     = (const float*)d_in[7];
    const float* enc_b     = (const float*)d_in[8];
    const float* pre_w     = (const float*)d_in[9];
    const float* pre_b     = (const float*)d_in[10];
    const float* post_w    = (const float*)d_in[11];
    const float* post_b    = (const float*)d_in[12];
    const float* lin_w     = (const float*)d_in[13];
    const float* lin_b     = (const float*)d_in[14];
    const float* bn_g      = (const float*)d_in[15];
    const float* bn_b      = (const float*)d_in[16];
    const float* w1 = (const float*)d_in[17];
    const float* b1 = (const float*)d_in[18];
    const float* w2 = (const float*)d_in[19];
    const float* b2 = (const float*)d_in[20];
    const float* w3 = (const float*)d_in[21];
    const float* b3 = (const float*)d_in[22];
    const int* srcp = eidx;
    const int* dstp = eidx + NE;
    float* out = (float*)d_out;

    char* ws = (char*)d_ws;
    size_t off = 0;
    auto alloc = [&](size_t bytes) -> char* {
        char* p = ws + off;
        off += (bytes + 255) & ~(size_t)255;
        return p;
    };
    float* h      = (float*)alloc((size_t)NN * H * 4);
    float* Abuf   = (float*)alloc((size_t)NN * TF * 4);   // reused as cbuf after k_agg
    float* Bbuf   = (float*)alloc((size_t)NN * TF * 4);
    float* base   = (float*)alloc((size_t)NN * BASE_W * 4);
    float* cpre   = (float*)alloc((size_t)NN * H * 4);
    float* ea_csr = (float*)alloc((size_t)NE * 12 * 4);   // P1/P2 alias this after last k_agg
    float* W3e    = (float*)alloc((size_t)EFD * TF * 4);
    float* dvecF  = (float*)alloc((size_t)TF * 4);
    float* p1T    = (float*)alloc((size_t)TF * H * 4);
    float* p2T    = (float*)alloc((size_t)TF * H * 4);
    float* W1e    = (float*)alloc((size_t)EFD * 52 * 4);
    float* b1e    = (float*)alloc((size_t)64 * 4);
    float* amp    = (float*)alloc((size_t)NN * 4);
    float* att    = (float*)alloc((size_t)NN * 4);
    float* avgs   = (float*)alloc(256);
    float* bnz    = (float*)alloc(512);
    int* cnt_i    = (int*)alloc((size_t)NN * 4);
    int* offs     = (int*)alloc((size_t)(NN + 1) * 4);
    int* fill     = (int*)alloc((size_t)NN * 4);
    if (off > ws_size) return;

    float* cbuf = Abuf;                      // safe: A dead after k_agg, cbuf dead before next k_ab
    float* P1 = ea_csr;                      // safe: ea_csr dead after last k_agg
    float* P2 = ea_csr + (size_t)NN * PSTR;  // 5.2 MB offset, 16B aligned

    hipMemsetAsync(cnt_i, 0, (size_t)NN * 4, stream);
    hipMemsetAsync(fill, 0, (size_t)NN * 4, stream);
    hipMemsetAsync(avgs, 0, 4, stream);

    k_deg<<<(NE + 255) / 256, 256, 0, stream>>>(dstp, cnt_i);
    k_avglog<<<64, 256, 0, stream>>>(cnt_i, avgs);
    k_ampatt<<<(NN + 255) / 256, 256, 0, stream>>>(cnt_i, avgs, amp, att);
    k_node_enc<<<(NN * H + 255) / 256, 256, 0, stream>>>(x, node_w, node_b, h);
    k_scan<<<1, 1024, 0, stream>>>(cnt_i, offs);
    k_scatter<<<(NE + 255) / 256, 256, 0, stream>>>(srcp, dstp, edge_attr, offs, fill, ea_csr);

    for (int layer = 0; layer < LAYERS; layer++) {
        k_prep1<<<(EFD * TF + TF * H + 255) / 256, 256, 0, stream>>>(
            enc_w, enc_b, edge_w, edge_b, pre_w, pre_b, W3e, dvecF, p1T, p2T, layer);
        k_ab<<<(NN * TF + 255) / 256, 256, 0, stream>>>(h, p1T, p2T, Abuf, Bbuf);
        k_agg<<<NN, 256, 0, stream>>>(ea_csr, Bbuf, Abuf, W3e, dvecF, cnt_i, offs, base);
        k_post<<<dim3((NN + 31) / 32, T), 256, 0, stream>>>(h, base, amp, att, post_w, post_b, cpre, layer);
        k_lin<<<(NN * H + 255) / 256, 256, 0, stream>>>(cpre, lin_w, lin_b, cbuf, layer);
        hipMemsetAsync(bnz, 0, 320, stream);
        k_bnstats<<<64, 320, 0, stream>>>(cbuf, bnz, bnz + 40);
        k_bnapply<<<(NN * H + 255) / 256, 256, 0, stream>>>(cbuf, bnz, bnz + 40, bn_g, bn_b, h, layer);
    }
    k_prep2<<<(EFD * 50 + NN * 50 + 255) / 256, 256, 0, stream>>>(
        edge_w, edge_b, w1, b1, h, W1e, b1e, P1, P2);
    k_mlp<<<(NE + 255) / 256, 256, 0, stream>>>(edge_attr, P1, P2, srcp, dstp,
                                                W1e, b1e, w2, b2, w3, b3, out);
}

// Round 4
// 713.914 us; speedup vs baseline: 1.8290x; 1.2985x over previous
//
#include <hip/hip_runtime.h>
#include <cstdint>
#include <cstddef>

#define NN 25000
#define NE 400000
#define NFD 30
#define EFD 10
#define H 40
#define T 5
#define FO 8
#define LAYERS 2
#define TF 200          // T*F
#define BASE_W 800      // T*160
#define PSTR 52         // padded row stride for P1/P2
#define CHUNK 128       // edges staged in LDS per round in k_agg
#define WS_PAD 532      // padded LDS row stride (floats) for post weights
#define ABN 64          // nodes per block in k_ab
#define EPSV 1e-5f

// ---------- degree histogram ----------
__global__ __launch_bounds__(256) void k_deg(const int* __restrict__ dst, int* __restrict__ cnt) {
    int e = blockIdx.x * 256 + threadIdx.x;
    if (e < NE) atomicAdd(&cnt[dst[e]], 1);
}

// ---------- sum of log(cnt+1) ----------
__global__ __launch_bounds__(256) void k_avglog(const int* __restrict__ cnt, float* __restrict__ slot) {
    __shared__ float red[256];
    float s = 0.0f;
    for (int i = blockIdx.x * 256 + threadIdx.x; i < NN; i += gridDim.x * 256)
        s += logf((float)cnt[i] + 1.0f);
    red[threadIdx.x] = s; __syncthreads();
    for (int o = 128; o > 0; o >>= 1) {
        if (threadIdx.x < o) red[threadIdx.x] += red[threadIdx.x + o];
        __syncthreads();
    }
    if (threadIdx.x == 0) atomicAdd(slot, red[0]);
}

// ---------- per-node amp/att ----------
__global__ __launch_bounds__(256) void k_ampatt(const int* __restrict__ cnt, const float* __restrict__ slot,
                                                float* __restrict__ amp, float* __restrict__ att) {
    int i = blockIdx.x * 256 + threadIdx.x;
    if (i >= NN) return;
    float avg = slot[0] / (float)NN;
    float c1 = fmaxf((float)cnt[i], 1.0f);
    float lg = logf(c1 + 1.0f);
    amp[i] = lg / avg;
    att[i] = avg / lg;
}

// ---------- h0 = x @ node_w + node_b ----------
__global__ __launch_bounds__(256) void k_node_enc(const float* __restrict__ x, const float* __restrict__ w,
                                                  const float* __restrict__ b, float* __restrict__ h) {
    int id = blockIdx.x * 256 + threadIdx.x;
    if (id >= NN * H) return;
    int n = id / H, j = id - n * H;
    const float* xr = x + (size_t)n * NFD;
    float acc = b[j];
    #pragma unroll
    for (int m = 0; m < NFD; m++) acc += xr[m] * w[m * H + j];
    h[id] = acc;
}

// ---------- exclusive scan of cnt -> offsets (int4-chunked, 1 block) ----------
__global__ __launch_bounds__(1024) void k_scan(const int* __restrict__ cnt, int* __restrict__ offs) {
    __shared__ int buf[1024];
    __shared__ int runbase;
    int tid = threadIdx.x;
    if (tid == 0) runbase = 0;
    __syncthreads();
    for (int base = 0; base < NN; base += 4096) {
        int i0 = base + tid * 4;
        int4 v = make_int4(0, 0, 0, 0);
        if (i0 < NN) v = *(const int4*)(cnt + i0);   // NN % 4 == 0
        int tsum = v.x + v.y + v.z + v.w;
        buf[tid] = tsum; __syncthreads();
        for (int o = 1; o < 1024; o <<= 1) {
            int t = (tid >= o) ? buf[tid - o] : 0;
            __syncthreads();
            buf[tid] += t;
            __syncthreads();
        }
        int excl = runbase + buf[tid] - tsum;
        if (i0 < NN) {
            offs[i0]     = excl;
            offs[i0 + 1] = excl + v.x;
            offs[i0 + 2] = excl + v.x + v.y;
            offs[i0 + 3] = excl + v.x + v.y + v.z;
        }
        __syncthreads();
        if (tid == 1023) runbase += buf[1023];
        __syncthreads();
    }
    if (tid == 0) offs[NN] = runbase;
}

// ---------- scatter edges into CSR order: ea_csr[p] = [ea0..ea9, srcbits, pad] ----------
__global__ __launch_bounds__(256) void k_scatter(const int* __restrict__ src, const int* __restrict__ dst,
                                                 const float* __restrict__ edge_attr,
                                                 const int* __restrict__ offs, int* __restrict__ fill,
                                                 float* __restrict__ ea_csr) {
    int e = blockIdx.x * 256 + threadIdx.x;
    if (e >= NE) return;
    int d = dst[e];
    int p = offs[d] + atomicAdd(&fill[d], 1);
    const float2* ear = (const float2*)(edge_attr + (size_t)e * EFD);
    float* o = ea_csr + (size_t)p * 12;
    #pragma unroll
    for (int m2 = 0; m2 < 5; m2++) {
        float2 v = ear[m2];
        o[2 * m2] = v.x; o[2 * m2 + 1] = v.y;
    }
    o[10] = __int_as_float(src[e]);
    o[11] = 0.0f;
}

// ---------- per-layer prep: W3e/dvecF (fold enc+edge encoders into edge_attr weights) + p1T/p2T ----------
__global__ __launch_bounds__(256) void k_prep1(const float* __restrict__ enc_w, const float* __restrict__ enc_b,
                                               const float* __restrict__ edge_w, const float* __restrict__ edge_b,
                                               const float* __restrict__ pre_w, const float* __restrict__ pre_b,
                                               float* __restrict__ W3e, float* __restrict__ dvecF,
                                               float* __restrict__ p1T, float* __restrict__ p2T, int layer) {
    int id = blockIdx.x * 256 + threadIdx.x;
    if (id < EFD * TF) {
        int m = id / TF, j = id - m * TF;
        int t = j / H, f = j - t * H;
        const float* ew = enc_w + (size_t)layer * H * H;
        const float* pw = pre_w + (size_t)(layer * T + t) * 120 * H;
        float acc = 0.0f;
        for (int k = 0; k < H; k++) {
            float wk = edge_w[m * H + k];
            float g = 0.0f;
            #pragma unroll
            for (int o = 0; o < H; o++) g += ew[k * H + o] * pw[(80 + o) * H + f];
            acc += wk * g;
        }
        W3e[m * TF + j] = acc;
        if (m == 0) {
            const float* eb = enc_b + (size_t)layer * H;
            float dacc = pre_b[(size_t)(layer * T + t) * H + f];
            for (int o = 0; o < H; o++) {
                float ebe = eb[o];
                #pragma unroll
                for (int k = 0; k < H; k++) ebe += edge_b[k] * ew[k * H + o];
                dacc += ebe * pw[(80 + o) * H + f];
            }
            dvecF[j] = dacc;
        }
    } else if (id < EFD * TF + TF * H) {
        int id2 = id - EFD * TF;
        int j = id2 / H, m = id2 - j * H;
        int t = j / H, f = j - t * H;
        const float* pw = pre_w + (size_t)(layer * T + t) * 120 * H;
        p1T[id2] = pw[m * H + f];
        p2T[id2] = pw[(H + m) * H + f];
    }
}

// ---------- A = h@P1, B = h@P2 : 64-node tile in LDS, weight columns in registers ----------
__global__ __launch_bounds__(256) void k_ab(const float* __restrict__ h, const float* __restrict__ p1T,
                                            const float* __restrict__ p2T, float* __restrict__ A,
                                            float* __restrict__ B) {
    __shared__ float sh[ABN * H];
    int tid = threadIdx.x;
    int n0 = blockIdx.x * ABN;
    int nodes = NN - n0; if (nodes > ABN) nodes = ABN;
    int nflt4 = nodes * H / 4;               // H%4==0
    const float4* hsrc = (const float4*)(h + (size_t)n0 * H);
    float4* sh4 = (float4*)sh;
    for (int i = tid; i < nflt4; i += 256) sh4[i] = hsrc[i];
    __syncthreads();
    int j = tid;
    if (j >= TF) return;
    float w1r[H], w2r[H];
    const float4* w1p = (const float4*)(p1T + (size_t)j * H);
    const float4* w2p = (const float4*)(p2T + (size_t)j * H);
    #pragma unroll
    for (int m4 = 0; m4 < H / 4; m4++) {
        float4 a = w1p[m4], b = w2p[m4];
        w1r[4 * m4] = a.x; w1r[4 * m4 + 1] = a.y; w1r[4 * m4 + 2] = a.z; w1r[4 * m4 + 3] = a.w;
        w2r[4 * m4] = b.x; w2r[4 * m4 + 1] = b.y; w2r[4 * m4 + 2] = b.z; w2r[4 * m4 + 3] = b.w;
    }
    for (int n = 0; n < nodes; n++) {
        const float4* hr = (const float4*)(sh + n * H);
        float a = 0.0f, b = 0.0f;
        #pragma unroll
        for (int m4 = 0; m4 < H / 4; m4++) {
            float4 hv = hr[m4];                       // same addr all lanes -> LDS broadcast
            a += hv.x * w1r[4 * m4]     + hv.y * w1r[4 * m4 + 1]
               + hv.z * w1r[4 * m4 + 2] + hv.w * w1r[4 * m4 + 3];
            b += hv.x * w2r[4 * m4]     + hv.y * w2r[4 * m4 + 1]
               + hv.z * w2r[4 * m4 + 2] + hv.w * w2r[4 * m4 + 3];
        }
        size_t o = (size_t)(n0 + n) * TF + j;         // lanes j consecutive -> coalesced
        A[o] = a;
        B[o] = b;
    }
}

// ---------- aggregation: block per node, LDS-staged edges, 1 global load per edge-iter ----------
__global__ __launch_bounds__(256) void k_agg(const float* __restrict__ ea_csr, const float* __restrict__ B,
                                             const float* __restrict__ A, const float* __restrict__ w3e,
                                             const float* __restrict__ dvecF, const int* __restrict__ cnt,
                                             const int* __restrict__ offs, float* __restrict__ base) {
    __shared__ float4 sea4[CHUNK * 3];
    int n = blockIdx.x;
    int tid = threadIdx.x;
    int j = tid;
    int deg = cnt[n];
    int start = offs[n];
    float w3c[EFD];
    float dj = 0.0f, a = 0.0f;
    if (j < TF) {
        #pragma unroll
        for (int m = 0; m < EFD; m++) w3c[m] = w3e[m * TF + j];
        dj = dvecF[j];
        a = A[(size_t)n * TF + j];
    }
    float s = 0.0f, q = 0.0f, mn = 3.4e38f, mx = -3.4e38f;
    int nchunks = (deg + CHUNK - 1) / CHUNK;
    for (int c = 0; c < nchunks; c++) {
        int count = deg - c * CHUNK;
        if (count > CHUNK) count = CHUNK;
        const float4* gsrc = (const float4*)(ea_csr + (size_t)(start + c * CHUNK) * 12);
        int nf4 = count * 3;
        for (int i = tid; i < nf4; i += 256) sea4[i] = gsrc[i];
        __syncthreads();
        if (j < TF) {
            int r = 0;
            for (; r + 2 <= count; r += 2) {
                float4 qa0 = sea4[r * 3],     qb0 = sea4[r * 3 + 1], qc0 = sea4[r * 3 + 2];
                float4 qa1 = sea4[r * 3 + 3], qb1 = sea4[r * 3 + 4], qc1 = sea4[r * 3 + 5];
                int sn0 = __float_as_int(qc0.z);
                int sn1 = __float_as_int(qc1.z);
                float b0 = B[(size_t)sn0 * TF + j];
                float b1 = B[(size_t)sn1 * TF + j];
                float C0 = dj + qa0.x * w3c[0] + qa0.y * w3c[1] + qa0.z * w3c[2] + qa0.w * w3c[3]
                              + qb0.x * w3c[4] + qb0.y * w3c[5] + qb0.z * w3c[6] + qb0.w * w3c[7]
                              + qc0.x * w3c[8] + qc0.y * w3c[9];
                float C1 = dj + qa1.x * w3c[0] + qa1.y * w3c[1] + qa1.z * w3c[2] + qa1.w * w3c[3]
                              + qb1.x * w3c[4] + qb1.y * w3c[5] + qb1.z * w3c[6] + qb1.w * w3c[7]
                              + qc1.x * w3c[8] + qc1.y * w3c[9];
                float u0 = b0 + C0;
                float u1 = b1 + C1;
                s += u0; q += u0 * u0; mn = fminf(mn, u0); mx = fmaxf(mx, u0);
                s += u1; q += u1 * u1; mn = fminf(mn, u1); mx = fmaxf(mx, u1);
            }
            if (r < count) {
                float4 qa = sea4[r * 3], qb = sea4[r * 3 + 1], qc = sea4[r * 3 + 2];
                int sn = __float_as_int(qc.z);
                float b0 = B[(size_t)sn * TF + j];
                float C = dj + qa.x * w3c[0] + qa.y * w3c[1] + qa.z * w3c[2] + qa.w * w3c[3]
                             + qb.x * w3c[4] + qb.y * w3c[5] + qb.z * w3c[6] + qb.w * w3c[7]
                             + qc.x * w3c[8] + qc.y * w3c[9];
                float u = b0 + C;
                s += u; q += u * u; mn = fminf(mn, u); mx = fmaxf(mx, u);
            }
        }
        __syncthreads();
    }
    if (j < TF) {
        float d = (float)deg, c1 = fmaxf(d, 1.0f);
        float mean = (d * a + s) / c1;
        float msq  = (d * a * a + 2.0f * a * s + q) / c1;
        float sd   = sqrtf(fmaxf(msq - mean * mean, 0.0f) + EPSV);
        float mnv = (deg > 0) ? (a + mn) : 0.0f;
        float mxv = (deg > 0) ? (a + mx) : 0.0f;
        int t = j / H, f = j - t * H;
        float* bb = base + (size_t)n * BASE_W + t * 160 + f;
        bb[0]   = mean;
        bb[40]  = mnv;
        bb[80]  = mxv;
        bb[120] = sd;
    }
}

// ---------- post einsum, t-split: block = 32 nodes x 8 outputs, weight slice in LDS ----------
__global__ __launch_bounds__(256) void k_post(const float* __restrict__ h, const float* __restrict__ base,
                                              const float* __restrict__ amp, const float* __restrict__ att,
                                              const float* __restrict__ post_w, const float* __restrict__ post_b,
                                              float* __restrict__ cpre, int layer) {
    __shared__ float ws[FO * WS_PAD];
    int tid = threadIdx.x;
    int t = blockIdx.y;
    const float* pwsrc = post_w + (size_t)(layer * T + t) * 520 * FO;
    for (int i = tid; i < 520 * FO; i += 256) {
        int g = i >> 3, o = i & 7;
        ws[o * WS_PAD + g] = pwsrc[i];
    }
    __syncthreads();
    int nl = tid >> 3, o = tid & 7;
    int n = blockIdx.x * 32 + nl;
    if (n >= NN) return;
    const float* wrow = ws + o * WS_PAD;
    float am = amp[n], at = att[n];
    float acc = post_b[(size_t)(layer * T + t) * FO + o];
    const float4* hx = (const float4*)(h + (size_t)n * H);
    #pragma unroll
    for (int g4 = 0; g4 < 10; g4++) {
        float4 xv = hx[g4];
        float4 wv = *(const float4*)(wrow + g4 * 4);
        acc += xv.x * wv.x + xv.y * wv.y + xv.z * wv.z + xv.w * wv.w;
    }
    const float4* br = (const float4*)(base + (size_t)n * BASE_W + t * 160);
    #pragma unroll
    for (int g4 = 0; g4 < 40; g4++) {
        float4 bv = br[g4];
        float4 wa = *(const float4*)(wrow + 40 + g4 * 4);
        float4 wb = *(const float4*)(wrow + 200 + g4 * 4);
        float4 wc = *(const float4*)(wrow + 360 + g4 * 4);
        acc += bv.x * (wa.x + am * wb.x + at * wc.x);
        acc += bv.y * (wa.y + am * wb.y + at * wc.y);
        acc += bv.z * (wa.z + am * wb.z + at * wc.z);
        acc += bv.w * (wa.w + am * wb.w + at * wc.w);
    }
    cpre[(size_t)n * H + t * FO + o] = acc;
}

// ---------- lin: cbuf = cpre @ lin_w + lin_b ----------
__global__ __launch_bounds__(256) void k_lin(const float* __restrict__ cpre, const float* __restrict__ lin_w,
                                             const float* __restrict__ lin_b, float* __restrict__ cbuf, int layer) {
    int id = blockIdx.x * 256 + threadIdx.x;
    if (id >= NN * H) return;
    int n = id / H, q = id - n * H;
    const float* cr = cpre + (size_t)n * H;
    const float* lw = lin_w + (size_t)layer * H * H;
    float acc = lin_b[(size_t)layer * H + q];
    #pragma unroll
    for (int k = 0; k < H; k++) acc += cr[k] * lw[k * H + q];
    cbuf[id] = acc;
}

// ---------- BN stats ----------
__global__ __launch_bounds__(320) void k_bnstats(const float* __restrict__ cbuf,
                                                 float* __restrict__ bnsum, float* __restrict__ bnsq) {
    __shared__ float ls[320], lq[320];
    int tid = threadIdx.x;
    int stride = gridDim.x * 320;
    float s = 0.0f, q = 0.0f;
    for (int idx = blockIdx.x * 320 + tid; idx < NN * H; idx += stride) {
        float v = cbuf[idx];
        s += v; q += v * v;
    }
    ls[tid] = s; lq[tid] = q;
    __syncthreads();
    if (tid < H) {
        float ss = 0.0f, qq = 0.0f;
        #pragma unroll
        for (int r = 0; r < 8; r++) { ss += ls[r * H + tid]; qq += lq[r * H + tid]; }
        atomicAdd(&bnsum[tid], ss);
        atomicAdd(&bnsq[tid], qq);
    }
}

// ---------- BN apply + residual ----------
__global__ __launch_bounds__(256) void k_bnapply(const float* __restrict__ cbuf, const float* __restrict__ bnsum,
                                                 const float* __restrict__ bnsq, const float* __restrict__ bn_g,
                                                 const float* __restrict__ bn_b, float* __restrict__ h, int layer) {
    int id = blockIdx.x * 256 + threadIdx.x;
    if (id >= NN * H) return;
    int j = id % H;
    float mu = bnsum[j] / (float)NN;
    float var = bnsq[j] / (float)NN - mu * mu;
    float inv = rsqrtf(var + EPSV);
    float cv = (cbuf[id] - mu) * inv * bn_g[(size_t)layer * H + j] + bn_b[(size_t)layer * H + j];
    h[id] = (h[id] + fmaxf(cv, 0.0f)) * 0.5f;
}

// ---------- final prep: W1e/b1e fold + P1/P2 node partials ----------
__global__ __launch_bounds__(256) void k_prep2(const float* __restrict__ edge_w, const float* __restrict__ edge_b,
                                               const float* __restrict__ w1, const float* __restrict__ b1,
                                               const float* __restrict__ h,
                                               float* __restrict__ W1e, float* __restrict__ b1e,
                                               float* __restrict__ P1, float* __restrict__ P2) {
    int id = blockIdx.x * 256 + threadIdx.x;
    if (id < EFD * 50) {
        int m = id / 50, o = id - m * 50;
        float acc = 0.0f;
        #pragma unroll
        for (int k = 0; k < H; k++) acc += edge_w[m * H + k] * w1[(80 + k) * 50 + o];
        W1e[m * 52 + o] = acc;
        if (m == 0) {
            float bacc = b1[o];
            #pragma unroll
            for (int k = 0; k < H; k++) bacc += edge_b[k] * w1[(80 + k) * 50 + o];
            b1e[o] = bacc;
        }
        if (o >= 48) { W1e[m * 52 + o + 2] = 0.0f; if (m == 0) b1e[o + 2] = 0.0f; }
    } else if (id < EFD * 50 + NN * 50) {
        int id2 = id - EFD * 50;
        int n = id2 / 50, o = id2 - n * 50;
        const float* hr = h + (size_t)n * H;
        float a1 = 0.0f, a2 = 0.0f;
        #pragma unroll
        for (int f = 0; f < H; f++) {
            float v = fmaxf(hr[f], 0.0f);
            a1 += v * w1[f * 50 + o];
            a2 += v * w1[(H + f) * 50 + o];
        }
        P1[(size_t)n * PSTR + o] = a1;
        P2[(size_t)n * PSTR + o] = a2;
    }
}

// ---------- final edge MLP, weights staged in LDS ----------
__global__ __launch_bounds__(256) void k_mlp(const float* __restrict__ edge_attr, const float* __restrict__ P1,
                                             const float* __restrict__ P2, const int* __restrict__ srcp,
                                             const int* __restrict__ dstp, const float* __restrict__ W1e,
                                             const float* __restrict__ b1e, const float* __restrict__ w2,
                                             const float* __restrict__ b2, const float* __restrict__ w3,
                                             const float* __restrict__ b3, float* __restrict__ out) {
    __shared__ float sW1[EFD * 52];   // padded to 52
    __shared__ float sb1[52];
    __shared__ float sw2[50 * 28];    // padded to 28
    __shared__ float sw3[50];
    __shared__ float sb2[25];
    __shared__ float sb3[2];
    int tid = threadIdx.x;
    for (int i = tid; i < EFD * 52; i += 256) sW1[i] = W1e[i];
    for (int i = tid; i < 52; i += 256) sb1[i] = b1e[i];
    for (int i = tid; i < 50 * 28; i += 256) {
        int k = i / 28, o = i - k * 28;
        sw2[i] = (o < 25) ? w2[k * 25 + o] : 0.0f;
    }
    for (int i = tid; i < 50; i += 256) sw3[i] = w3[i];
    for (int i = tid; i < 25; i += 256) sb2[i] = b2[i];
    if (tid < 2) sb3[tid] = b3[tid];
    __syncthreads();

    int e = blockIdx.x * 256 + tid;
    if (e >= NE) return;
    int s = srcp[e], d = dstp[e];
    float z1[52];
    const float4* p1r = (const float4*)(P1 + (size_t)s * PSTR);
    const float4* p2r = (const float4*)(P2 + (size_t)d * PSTR);
    #pragma unroll
    for (int i = 0; i < 13; i++) {
        float4 a = p1r[i], b = p2r[i];
        z1[4 * i]     = a.x + b.x + sb1[4 * i];
        z1[4 * i + 1] = a.y + b.y + sb1[4 * i + 1];
        z1[4 * i + 2] = a.z + b.z + sb1[4 * i + 2];
        z1[4 * i + 3] = a.w + b.w + sb1[4 * i + 3];
    }
    const float2* ea2 = (const float2*)(edge_attr + (size_t)e * EFD);
    #pragma unroll
    for (int m2 = 0; m2 < 5; m2++) {
        float2 v = ea2[m2];
        const float* wr0 = sW1 + (2 * m2) * 52;
        const float* wr1 = sW1 + (2 * m2 + 1) * 52;
        #pragma unroll
        for (int i = 0; i < 13; i++) {
            float4 w0 = *(const float4*)(wr0 + 4 * i);
            float4 w1v = *(const float4*)(wr1 + 4 * i);
            z1[4 * i]     += v.x * w0.x + v.y * w1v.x;
            z1[4 * i + 1] += v.x * w0.y + v.y * w1v.y;
            z1[4 * i + 2] += v.x * w0.z + v.y * w1v.z;
            z1[4 * i + 3] += v.x * w0.w + v.y * w1v.w;
        }
    }
    float z2[28];
    #pragma unroll
    for (int o = 0; o < 25; o++) z2[o] = sb2[o];
    z2[25] = z2[26] = z2[27] = 0.0f;
    #pragma unroll
    for (int k = 0; k < 50; k++) {
        float v = fmaxf(z1[k], 0.0f);
        const float* wr = sw2 + k * 28;
        #pragma unroll
        for (int i = 0; i < 7; i++) {
            float4 w = *(const float4*)(wr + 4 * i);
            z2[4 * i]     += v * w.x;
            z2[4 * i + 1] += v * w.y;
            z2[4 * i + 2] += v * w.z;
            z2[4 * i + 3] += v * w.w;
        }
    }
    float o0 = sb3[0], o1 = sb3[1];
    #pragma unroll
    for (int k = 0; k < 25; k++) {
        float v = fmaxf(z2[k], 0.0f);
        o0 += v * sw3[k * 2];
        o1 += v * sw3[k * 2 + 1];
    }
    out[(size_t)e * 2]     = o0;
    out[(size_t)e * 2 + 1] = o1;
}

extern "C" void kernel_launch(void* const* d_in, const int* in_sizes, int n_in,
                              void* d_out, int out_size, void* d_ws, size_t ws_size,
                              hipStream_t stream) {
    const float* x         = (const float*)d_in[0];
    const float* edge_attr = (const float*)d_in[1];
    const int*   eidx      = (const int*)  d_in[2];
    const float* node_w    = (const float*)d_in[3];
    const float* node_b    = (const float*)d_in[4];
    const float* edge_w    = (const float*)d_in[5];
    const float* edge_b    = (const float*)d_in[6];
    const float* enc_w     = (const float*)d_in[7];
    const float* enc_b     = (const float*)d_in[8];
    const float* pre_w     = (const float*)d_in[9];
    const float* pre_b     = (const float*)d_in[10];
    const float* post_w    = (const float*)d_in[11];
    const float* post_b    = (const float*)d_in[12];
    const float* lin_w     = (const float*)d_in[13];
    const float* lin_b     = (const float*)d_in[14];
    const float* bn_g      = (const float*)d_in[15];
    const float* bn_b      = (const float*)d_in[16];
    const float* w1 = (const float*)d_in[17];
    const float* b1 = (const float*)d_in[18];
    const float* w2 = (const float*)d_in[19];
    const float* b2 = (const float*)d_in[20];
    const float* w3 = (const float*)d_in[21];
    const float* b3 = (const float*)d_in[22];
    const int* srcp = eidx;
    const int* dstp = eidx + NE;
    float* out = (float*)d_out;

    char* ws = (char*)d_ws;
    size_t off = 0;
    auto alloc = [&](size_t bytes) -> char* {
        char* p = ws + off;
        off += (bytes + 255) & ~(size_t)255;
        return p;
    };
    float* h      = (float*)alloc((size_t)NN * H * 4);
    float* Abuf   = (float*)alloc((size_t)NN * TF * 4);   // reused as cbuf after k_agg
    float* Bbuf   = (float*)alloc((size_t)NN * TF * 4);
    float* base   = (float*)alloc((size_t)NN * BASE_W * 4);
    float* cpre   = (float*)alloc((size_t)NN * H * 4);
    float* ea_csr = (float*)alloc((size_t)NE * 12 * 4);   // P1/P2 alias this after last k_agg
    float* W3e    = (float*)alloc((size_t)EFD * TF * 4);
    float* dvecF  = (float*)alloc((size_t)TF * 4);
    float* p1T    = (float*)alloc((size_t)TF * H * 4);
    float* p2T    = (float*)alloc((size_t)TF * H * 4);
    float* W1e    = (float*)alloc((size_t)EFD * 52 * 4);
    float* b1e    = (float*)alloc((size_t)64 * 4);
    float* amp    = (float*)alloc((size_t)NN * 4);
    float* att    = (float*)alloc((size_t)NN * 4);
    float* avgs   = (float*)alloc(256);
    float* bnz    = (float*)alloc(512);
    int* cnt_i    = (int*)alloc((size_t)NN * 4);
    int* offs     = (int*)alloc((size_t)(NN + 1) * 4);
    int* fill     = (int*)alloc((size_t)NN * 4);
    if (off > ws_size) return;

    float* cbuf = Abuf;                      // safe: A dead after k_agg, cbuf dead before next k_ab
    float* P1 = ea_csr;                      // safe: ea_csr dead after last k_agg
    float* P2 = ea_csr + (size_t)NN * PSTR;  // 5.2 MB offset, 16B aligned

    hipMemsetAsync(cnt_i, 0, (size_t)NN * 4, stream);
    hipMemsetAsync(fill, 0, (size_t)NN * 4, stream);
    hipMemsetAsync(avgs, 0, 4, stream);

    k_deg<<<(NE + 255) / 256, 256, 0, stream>>>(dstp, cnt_i);
    k_avglog<<<64, 256, 0, stream>>>(cnt_i, avgs);
    k_ampatt<<<(NN + 255) / 256, 256, 0, stream>>>(cnt_i, avgs, amp, att);
    k_node_enc<<<(NN * H + 255) / 256, 256, 0, stream>>>(x, node_w, node_b, h);
    k_scan<<<1, 1024, 0, stream>>>(cnt_i, offs);
    k_scatter<<<(NE + 255) / 256, 256, 0, stream>>>(srcp, dstp, edge_attr, offs, fill, ea_csr);

    for (int layer = 0; layer < LAYERS; layer++) {
        k_prep1<<<(EFD * TF + TF * H + 255) / 256, 256, 0, stream>>>(
            enc_w, enc_b, edge_w, edge_b, pre_w, pre_b, W3e, dvecF, p1T, p2T, layer);
        k_ab<<<(NN + ABN - 1) / ABN, 256, 0, stream>>>(h, p1T, p2T, Abuf, Bbuf);
        k_agg<<<NN, 256, 0, stream>>>(ea_csr, Bbuf, Abuf, W3e, dvecF, cnt_i, offs, base);
        k_post<<<dim3((NN + 31) / 32, T), 256, 0, stream>>>(h, base, amp, att, post_w, post_b, cpre, layer);
        k_lin<<<(NN * H + 255) / 256, 256, 0, stream>>>(cpre, lin_w, lin_b, cbuf, layer);
        hipMemsetAsync(bnz, 0, 320, stream);
        k_bnstats<<<64, 320, 0, stream>>>(cbuf, bnz, bnz + 40);
        k_bnapply<<<(NN * H + 255) / 256, 256, 0, stream>>>(cbuf, bnz, bnz + 40, bn_g, bn_b, h, layer);
    }
    k_prep2<<<(EFD * 50 + NN * 50 + 255) / 256, 256, 0, stream>>>(
        edge_w, edge_b, w1, b1, h, W1e, b1e, P1, P2);
    k_mlp<<<(NE + 255) / 256, 256, 0, stream>>>(edge_attr, P1, P2, srcp, dstp,
                                                W1e, b1e, w2, b2, w3, b3, out);
}

// Round 5
// 708.813 us; speedup vs baseline: 1.8422x; 1.0072x over previous
//
#include <hip/hip_runtime.h>
#include <cstdint>
#include <cstddef>

#define NN 25000
#define NE 400000
#define NFD 30
#define EFD 10
#define H 40
#define T 5
#define FO 8
#define LAYERS 2
#define TF 200          // T*F
#define BASE_W 800      // T*160
#define PSTR 52         // padded row stride for P1/P2
#define CHUNK 64        // edges staged in LDS per wave-round in k_agg
#define WS_PAD 532      // padded LDS row stride (floats) for post weights
#define ABN 64          // nodes per block in k_ab
#define REC 16          // floats per CSR edge record
#define EPSV 1e-5f

// ---------- degree histogram ----------
__global__ __launch_bounds__(256) void k_deg(const int* __restrict__ dst, int* __restrict__ cnt) {
    int e = blockIdx.x * 256 + threadIdx.x;
    if (e < NE) atomicAdd(&cnt[dst[e]], 1);
}

// ---------- sum of log(cnt+1) ----------
__global__ __launch_bounds__(256) void k_avglog(const int* __restrict__ cnt, float* __restrict__ slot) {
    __shared__ float red[256];
    float s = 0.0f;
    for (int i = blockIdx.x * 256 + threadIdx.x; i < NN; i += gridDim.x * 256)
        s += logf((float)cnt[i] + 1.0f);
    red[threadIdx.x] = s; __syncthreads();
    for (int o = 128; o > 0; o >>= 1) {
        if (threadIdx.x < o) red[threadIdx.x] += red[threadIdx.x + o];
        __syncthreads();
    }
    if (threadIdx.x == 0) atomicAdd(slot, red[0]);
}

// ---------- per-node amp/att ----------
__global__ __launch_bounds__(256) void k_ampatt(const int* __restrict__ cnt, const float* __restrict__ slot,
                                                float* __restrict__ amp, float* __restrict__ att) {
    int i = blockIdx.x * 256 + threadIdx.x;
    if (i >= NN) return;
    float avg = slot[0] / (float)NN;
    float c1 = fmaxf((float)cnt[i], 1.0f);
    float lg = logf(c1 + 1.0f);
    amp[i] = lg / avg;
    att[i] = avg / lg;
}

// ---------- h0 = x @ node_w + node_b ----------
__global__ __launch_bounds__(256) void k_node_enc(const float* __restrict__ x, const float* __restrict__ w,
                                                  const float* __restrict__ b, float* __restrict__ h) {
    int id = blockIdx.x * 256 + threadIdx.x;
    if (id >= NN * H) return;
    int n = id / H, j = id - n * H;
    const float* xr = x + (size_t)n * NFD;
    float acc = b[j];
    #pragma unroll
    for (int m = 0; m < NFD; m++) acc += xr[m] * w[m * H + j];
    h[id] = acc;
}

// ---------- exclusive scan of cnt -> offsets (int4-chunked, 1 block) ----------
__global__ __launch_bounds__(1024) void k_scan(const int* __restrict__ cnt, int* __restrict__ offs) {
    __shared__ int buf[1024];
    __shared__ int runbase;
    int tid = threadIdx.x;
    if (tid == 0) runbase = 0;
    __syncthreads();
    for (int base = 0; base < NN; base += 4096) {
        int i0 = base + tid * 4;
        int4 v = make_int4(0, 0, 0, 0);
        if (i0 < NN) v = *(const int4*)(cnt + i0);   // NN % 4 == 0
        int tsum = v.x + v.y + v.z + v.w;
        buf[tid] = tsum; __syncthreads();
        for (int o = 1; o < 1024; o <<= 1) {
            int t = (tid >= o) ? buf[tid - o] : 0;
            __syncthreads();
            buf[tid] += t;
            __syncthreads();
        }
        int excl = runbase + buf[tid] - tsum;
        if (i0 < NN) {
            offs[i0]     = excl;
            offs[i0 + 1] = excl + v.x;
            offs[i0 + 2] = excl + v.x + v.y;
            offs[i0 + 3] = excl + v.x + v.y + v.z;
        }
        __syncthreads();
        if (tid == 1023) runbase += buf[1023];
        __syncthreads();
    }
    if (tid == 0) offs[NN] = runbase;
}

// ---------- scatter edges into CSR records [ea0..9, src, dst, eid, 0,0,0] ----------
__global__ __launch_bounds__(256) void k_scatter(const int* __restrict__ src, const int* __restrict__ dst,
                                                 const float* __restrict__ edge_attr,
                                                 const int* __restrict__ offs, int* __restrict__ fill,
                                                 float* __restrict__ ea_csr) {
    int e = blockIdx.x * 256 + threadIdx.x;
    if (e >= NE) return;
    int d = dst[e];
    int p = offs[d] + atomicAdd(&fill[d], 1);
    const float2* ear = (const float2*)(edge_attr + (size_t)e * EFD);
    float2 v0 = ear[0], v1 = ear[1], v2 = ear[2], v3 = ear[3], v4 = ear[4];
    float4* o = (float4*)(ea_csr + (size_t)p * REC);
    o[0] = make_float4(v0.x, v0.y, v1.x, v1.y);
    o[1] = make_float4(v2.x, v2.y, v3.x, v3.y);
    o[2] = make_float4(v4.x, v4.y, __int_as_float(src[e]), __int_as_float(d));
    o[3] = make_float4(__int_as_float(e), 0.0f, 0.0f, 0.0f);
}

// ---------- per-layer prep: W3e/dvecF + p1T/p2T + zero bn accumulators ----------
__global__ __launch_bounds__(256) void k_prep1(const float* __restrict__ enc_w, const float* __restrict__ enc_b,
                                               const float* __restrict__ edge_w, const float* __restrict__ edge_b,
                                               const float* __restrict__ pre_w, const float* __restrict__ pre_b,
                                               float* __restrict__ W3e, float* __restrict__ dvecF,
                                               float* __restrict__ p1T, float* __restrict__ p2T,
                                               float* __restrict__ bnz, int layer) {
    int id = blockIdx.x * 256 + threadIdx.x;
    if (id < EFD * TF) {
        int m = id / TF, j = id - m * TF;
        int t = j / H, f = j - t * H;
        const float* ew = enc_w + (size_t)layer * H * H;
        const float* pw = pre_w + (size_t)(layer * T + t) * 120 * H;
        float acc = 0.0f;
        for (int k = 0; k < H; k++) {
            float wk = edge_w[m * H + k];
            float g = 0.0f;
            #pragma unroll
            for (int o = 0; o < H; o++) g += ew[k * H + o] * pw[(80 + o) * H + f];
            acc += wk * g;
        }
        W3e[m * TF + j] = acc;
        if (m == 0) {
            const float* eb = enc_b + (size_t)layer * H;
            float dacc = pre_b[(size_t)(layer * T + t) * H + f];
            for (int o = 0; o < H; o++) {
                float ebe = eb[o];
                #pragma unroll
                for (int k = 0; k < H; k++) ebe += edge_b[k] * ew[k * H + o];
                dacc += ebe * pw[(80 + o) * H + f];
            }
            dvecF[j] = dacc;
        }
    } else if (id < EFD * TF + TF * H) {
        int id2 = id - EFD * TF;
        int j = id2 / H, m = id2 - j * H;
        int t = j / H, f = j - t * H;
        const float* pw = pre_w + (size_t)(layer * T + t) * 120 * H;
        p1T[id2] = pw[m * H + f];
        p2T[id2] = pw[(H + m) * H + f];
    } else if (id < EFD * TF + TF * H + 80) {
        bnz[id - EFD * TF - TF * H] = 0.0f;   // zero bnsum/bnsq for this layer
    }
}

// ---------- A = h@P1, B = h@P2 : 64-node tile in LDS, weight columns in registers ----------
__global__ __launch_bounds__(256) void k_ab(const float* __restrict__ h, const float* __restrict__ p1T,
                                            const float* __restrict__ p2T, float* __restrict__ A,
                                            float* __restrict__ B) {
    __shared__ float sh[ABN * H];
    int tid = threadIdx.x;
    int n0 = blockIdx.x * ABN;
    int nodes = NN - n0; if (nodes > ABN) nodes = ABN;
    int nflt4 = nodes * H / 4;               // H%4==0
    const float4* hsrc = (const float4*)(h + (size_t)n0 * H);
    float4* sh4 = (float4*)sh;
    for (int i = tid; i < nflt4; i += 256) sh4[i] = hsrc[i];
    __syncthreads();
    int j = tid;
    if (j >= TF) return;
    float w1r[H], w2r[H];
    const float4* w1p = (const float4*)(p1T + (size_t)j * H);
    const float4* w2p = (const float4*)(p2T + (size_t)j * H);
    #pragma unroll
    for (int m4 = 0; m4 < H / 4; m4++) {
        float4 a = w1p[m4], b = w2p[m4];
        w1r[4 * m4] = a.x; w1r[4 * m4 + 1] = a.y; w1r[4 * m4 + 2] = a.z; w1r[4 * m4 + 3] = a.w;
        w2r[4 * m4] = b.x; w2r[4 * m4 + 1] = b.y; w2r[4 * m4 + 2] = b.z; w2r[4 * m4 + 3] = b.w;
    }
    for (int n = 0; n < nodes; n++) {
        const float4* hr = (const float4*)(sh + n * H);
        float a = 0.0f, b = 0.0f;
        #pragma unroll
        for (int m4 = 0; m4 < H / 4; m4++) {
            float4 hv = hr[m4];                       // same addr all lanes -> LDS broadcast
            a += hv.x * w1r[4 * m4]     + hv.y * w1r[4 * m4 + 1]
               + hv.z * w1r[4 * m4 + 2] + hv.w * w1r[4 * m4 + 3];
            b += hv.x * w2r[4 * m4]     + hv.y * w2r[4 * m4 + 1]
               + hv.z * w2r[4 * m4 + 2] + hv.w * w2r[4 * m4 + 3];
        }
        size_t o = (size_t)(n0 + n) * TF + j;         // lanes j consecutive -> coalesced
        A[o] = a;
        B[o] = b;
    }
}

// ---------- aggregation: wave per node (4 nodes/block), lane owns 4 consecutive j ----------
__global__ __launch_bounds__(256) void k_agg(const float* __restrict__ ea_csr, const float* __restrict__ B,
                                             const float* __restrict__ A, const float* __restrict__ w3e,
                                             const float* __restrict__ dvecF, const int* __restrict__ cnt,
                                             const int* __restrict__ offs, float* __restrict__ base) {
    __shared__ float4 sea4[4 * CHUNK * 4];   // 16 KB: per-wave region of CHUNK records
    __shared__ int s_nmax;
    int tid = threadIdx.x;
    int wid = tid >> 6;
    int lane = tid & 63;
    int n = blockIdx.x * 4 + wid;
    bool nvalid = (n < NN);
    int deg = nvalid ? cnt[n] : 0;
    int start = nvalid ? offs[n] : 0;
    int mych = (deg + CHUNK - 1) / CHUNK;
    if (tid == 0) s_nmax = 0;
    __syncthreads();
    if (lane == 0 && mych > 0) atomicMax(&s_nmax, mych);
    __syncthreads();
    int nmax = s_nmax;

    bool comp = nvalid && (lane < TF / 4);   // lanes 0..49
    float4 w3q[EFD];
    float4 dj4 = make_float4(0, 0, 0, 0), a4 = make_float4(0, 0, 0, 0);
    if (comp) {
        #pragma unroll
        for (int m = 0; m < EFD; m++) w3q[m] = *(const float4*)(w3e + m * TF + 4 * lane);
        dj4 = *(const float4*)(dvecF + 4 * lane);
        a4  = *(const float4*)(A + (size_t)n * TF + 4 * lane);
    }
    float sx = 0, sy = 0, sz = 0, sw_ = 0;
    float qx = 0, qy = 0, qz = 0, qw = 0;
    float mnx = 3.4e38f, mny = 3.4e38f, mnz = 3.4e38f, mnw = 3.4e38f;
    float mxx = -3.4e38f, mxy = -3.4e38f, mxz = -3.4e38f, mxw = -3.4e38f;
    float4* swp = sea4 + wid * CHUNK * 4;
    const float4* b4p = (const float4*)B;

    for (int c = 0; c < nmax; c++) {
        int count = deg - c * CHUNK;
        if (count > CHUNK) count = CHUNK;
        if (count > 0) {
            const float4* g4 = (const float4*)ea_csr + (size_t)(start + c * CHUNK) * 4;
            int nf = count * 4;
            for (int i = lane; i < nf; i += 64) swp[i] = g4[i];   // fully coalesced
        }
        __syncthreads();
        if (count > 0 && comp) {
            #pragma unroll 2
            for (int r = 0; r < count; r++) {
                float4 qa = swp[r * 4], qb = swp[r * 4 + 1], qc = swp[r * 4 + 2];
                int sn = __float_as_int(qc.z);
                float4 b4 = b4p[(size_t)sn * (TF / 4) + lane];
                float eav[EFD] = {qa.x, qa.y, qa.z, qa.w, qb.x, qb.y, qb.z, qb.w, qc.x, qc.y};
                float cx = dj4.x, cy = dj4.y, cz = dj4.z, cw = dj4.w;
                #pragma unroll
                for (int m = 0; m < EFD; m++) {
                    cx = fmaf(eav[m], w3q[m].x, cx);
                    cy = fmaf(eav[m], w3q[m].y, cy);
                    cz = fmaf(eav[m], w3q[m].z, cz);
                    cw = fmaf(eav[m], w3q[m].w, cw);
                }
                float ux = b4.x + cx, uy = b4.y + cy, uz = b4.z + cz, uw = b4.w + cw;
                sx += ux; qx = fmaf(ux, ux, qx); mnx = fminf(mnx, ux); mxx = fmaxf(mxx, ux);
                sy += uy; qy = fmaf(uy, uy, qy); mny = fminf(mny, uy); mxy = fmaxf(mxy, uy);
                sz += uz; qz = fmaf(uz, uz, qz); mnz = fminf(mnz, uz); mxz = fmaxf(mxz, uz);
                sw_ += uw; qw = fmaf(uw, uw, qw); mnw = fminf(mnw, uw); mxw = fmaxf(mxw, uw);
            }
        }
        __syncthreads();
    }
    if (comp) {
        float d = (float)deg, c1 = fmaxf(d, 1.0f);
        float inv = 1.0f / c1;
        float mex = (d * a4.x + sx) * inv, mey = (d * a4.y + sy) * inv;
        float mez = (d * a4.z + sz) * inv, mew = (d * a4.w + sw_) * inv;
        float msx = (d * a4.x * a4.x + 2.0f * a4.x * sx + qx) * inv;
        float msy = (d * a4.y * a4.y + 2.0f * a4.y * sy + qy) * inv;
        float msz = (d * a4.z * a4.z + 2.0f * a4.z * sz + qz) * inv;
        float msw = (d * a4.w * a4.w + 2.0f * a4.w * sw_ + qw) * inv;
        float4 mean4 = make_float4(mex, mey, mez, mew);
        float4 sd4 = make_float4(sqrtf(fmaxf(msx - mex * mex, 0.0f) + EPSV),
                                 sqrtf(fmaxf(msy - mey * mey, 0.0f) + EPSV),
                                 sqrtf(fmaxf(msz - mez * mez, 0.0f) + EPSV),
                                 sqrtf(fmaxf(msw - mew * mew, 0.0f) + EPSV));
        bool has = deg > 0;
        float4 mnv4 = has ? make_float4(a4.x + mnx, a4.y + mny, a4.z + mnz, a4.w + mnw)
                          : make_float4(0, 0, 0, 0);
        float4 mxv4 = has ? make_float4(a4.x + mxx, a4.y + mxy, a4.z + mxz, a4.w + mxw)
                          : make_float4(0, 0, 0, 0);
        int j0 = 4 * lane;
        int t = j0 / H, f = j0 - t * H;
        float* bb = base + (size_t)n * BASE_W + t * 160 + f;
        *(float4*)(bb)       = mean4;
        *(float4*)(bb + 40)  = mnv4;
        *(float4*)(bb + 80)  = mxv4;
        *(float4*)(bb + 120) = sd4;
    }
}

// ---------- post einsum, t-split: block = 32 nodes x 8 outputs, weight slice in LDS ----------
__global__ __launch_bounds__(256) void k_post(const float* __restrict__ h, const float* __restrict__ base,
                                              const float* __restrict__ amp, const float* __restrict__ att,
                                              const float* __restrict__ post_w, const float* __restrict__ post_b,
                                              float* __restrict__ cpre, int layer) {
    __shared__ float ws[FO * WS_PAD];
    int tid = threadIdx.x;
    int t = blockIdx.y;
    const float* pwsrc = post_w + (size_t)(layer * T + t) * 520 * FO;
    for (int i = tid; i < 520 * FO; i += 256) {
        int g = i >> 3, o = i & 7;
        ws[o * WS_PAD + g] = pwsrc[i];
    }
    __syncthreads();
    int nl = tid >> 3, o = tid & 7;
    int n = blockIdx.x * 32 + nl;
    if (n >= NN) return;
    const float* wrow = ws + o * WS_PAD;
    float am = amp[n], at = att[n];
    float acc = post_b[(size_t)(layer * T + t) * FO + o];
    const float4* hx = (const float4*)(h + (size_t)n * H);
    #pragma unroll
    for (int g4 = 0; g4 < 10; g4++) {
        float4 xv = hx[g4];
        float4 wv = *(const float4*)(wrow + g4 * 4);
        acc += xv.x * wv.x + xv.y * wv.y + xv.z * wv.z + xv.w * wv.w;
    }
    const float4* br = (const float4*)(base + (size_t)n * BASE_W + t * 160);
    #pragma unroll
    for (int g4 = 0; g4 < 40; g4++) {
        float4 bv = br[g4];
        float4 wa = *(const float4*)(wrow + 40 + g4 * 4);
        float4 wb = *(const float4*)(wrow + 200 + g4 * 4);
        float4 wc = *(const float4*)(wrow + 360 + g4 * 4);
        acc += bv.x * (wa.x + am * wb.x + at * wc.x);
        acc += bv.y * (wa.y + am * wb.y + at * wc.y);
        acc += bv.z * (wa.z + am * wb.z + at * wc.z);
        acc += bv.w * (wa.w + am * wb.w + at * wc.w);
    }
    cpre[(size_t)n * H + t * FO + o] = acc;
}

// ---------- lin: cbuf = cpre @ lin_w + lin_b ----------
__global__ __launch_bounds__(256) void k_lin(const float* __restrict__ cpre, const float* __restrict__ lin_w,
                                             const float* __restrict__ lin_b, float* __restrict__ cbuf, int layer) {
    int id = blockIdx.x * 256 + threadIdx.x;
    if (id >= NN * H) return;
    int n = id / H, q = id - n * H;
    const float* cr = cpre + (size_t)n * H;
    const float* lw = lin_w + (size_t)layer * H * H;
    float acc = lin_b[(size_t)layer * H + q];
    #pragma unroll
    for (int k = 0; k < H; k++) acc += cr[k] * lw[k * H + q];
    cbuf[id] = acc;
}

// ---------- BN stats ----------
__global__ __launch_bounds__(320) void k_bnstats(const float* __restrict__ cbuf,
                                                 float* __restrict__ bnsum, float* __restrict__ bnsq) {
    __shared__ float ls[320], lq[320];
    int tid = threadIdx.x;
    int stride = gridDim.x * 320;
    float s = 0.0f, q = 0.0f;
    for (int idx = blockIdx.x * 320 + tid; idx < NN * H; idx += stride) {
        float v = cbuf[idx];
        s += v; q += v * v;
    }
    ls[tid] = s; lq[tid] = q;
    __syncthreads();
    if (tid < H) {
        float ss = 0.0f, qq = 0.0f;
        #pragma unroll
        for (int r = 0; r < 8; r++) { ss += ls[r * H + tid]; qq += lq[r * H + tid]; }
        atomicAdd(&bnsum[tid], ss);
        atomicAdd(&bnsq[tid], qq);
    }
}

// ---------- BN apply + residual ----------
__global__ __launch_bounds__(256) void k_bnapply(const float* __restrict__ cbuf, const float* __restrict__ bnsum,
                                                 const float* __restrict__ bnsq, const float* __restrict__ bn_g,
                                                 const float* __restrict__ bn_b, float* __restrict__ h, int layer) {
    int id = blockIdx.x * 256 + threadIdx.x;
    if (id >= NN * H) return;
    int j = id % H;
    float mu = bnsum[j] / (float)NN;
    float var = bnsq[j] / (float)NN - mu * mu;
    float inv = rsqrtf(var + EPSV);
    float cv = (cbuf[id] - mu) * inv * bn_g[(size_t)layer * H + j] + bn_b[(size_t)layer * H + j];
    h[id] = (h[id] + fmaxf(cv, 0.0f)) * 0.5f;
}

// ---------- final prep: W1e/b1e fold + P1/P2 node partials ----------
__global__ __launch_bounds__(256) void k_prep2(const float* __restrict__ edge_w, const float* __restrict__ edge_b,
                                               const float* __restrict__ w1, const float* __restrict__ b1,
                                               const float* __restrict__ h,
                                               float* __restrict__ W1e, float* __restrict__ b1e,
                                               float* __restrict__ P1, float* __restrict__ P2) {
    int id = blockIdx.x * 256 + threadIdx.x;
    if (id < EFD * 50) {
        int m = id / 50, o = id - m * 50;
        float acc = 0.0f;
        #pragma unroll
        for (int k = 0; k < H; k++) acc += edge_w[m * H + k] * w1[(80 + k) * 50 + o];
        W1e[m * 52 + o] = acc;
        if (m == 0) {
            float bacc = b1[o];
            #pragma unroll
            for (int k = 0; k < H; k++) bacc += edge_b[k] * w1[(80 + k) * 50 + o];
            b1e[o] = bacc;
        }
        if (o >= 48) { W1e[m * 52 + o + 2] = 0.0f; if (m == 0) b1e[o + 2] = 0.0f; }
    } else if (id < EFD * 50 + NN * 50) {
        int id2 = id - EFD * 50;
        int n = id2 / 50, o = id2 - n * 50;
        const float* hr = h + (size_t)n * H;
        float a1 = 0.0f, a2 = 0.0f;
        #pragma unroll
        for (int f = 0; f < H; f++) {
            float v = fmaxf(hr[f], 0.0f);
            a1 += v * w1[f * 50 + o];
            a2 += v * w1[(H + f) * 50 + o];
        }
        P1[(size_t)n * PSTR + o] = a1;
        P2[(size_t)n * PSTR + o] = a2;
    }
}

// ---------- final edge MLP over CSR order (dst-locality for P2), scatter out by eid ----------
__global__ __launch_bounds__(256) void k_mlp(const float* __restrict__ ea_csr, const float* __restrict__ P1,
                                             const float* __restrict__ P2, const float* __restrict__ W1e,
                                             const float* __restrict__ b1e, const float* __restrict__ w2,
                                             const float* __restrict__ b2, const float* __restrict__ w3,
                                             const float* __restrict__ b3, float* __restrict__ out) {
    __shared__ float sW1[EFD * 52];
    __shared__ float sb1[52];
    __shared__ float sw2[50 * 28];
    __shared__ float sw3[50];
    __shared__ float sb2[25];
    __shared__ float sb3[2];
    int tid = threadIdx.x;
    for (int i = tid; i < EFD * 52; i += 256) sW1[i] = W1e[i];
    for (int i = tid; i < 52; i += 256) sb1[i] = b1e[i];
    for (int i = tid; i < 50 * 28; i += 256) {
        int k = i / 28, o = i - k * 28;
        sw2[i] = (o < 25) ? w2[k * 25 + o] : 0.0f;
    }
    for (int i = tid; i < 50; i += 256) sw3[i] = w3[i];
    for (int i = tid; i < 25; i += 256) sb2[i] = b2[i];
    if (tid < 2) sb3[tid] = b3[tid];
    __syncthreads();

    int p = blockIdx.x * 256 + tid;
    if (p >= NE) return;
    const float4* rec = (const float4*)ea_csr + (size_t)p * 4;
    float4 r0 = rec[0], r1 = rec[1], r2 = rec[2], r3 = rec[3];
    int s = __float_as_int(r2.z), d = __float_as_int(r2.w), eid = __float_as_int(r3.x);
    float ea[EFD] = {r0.x, r0.y, r0.z, r0.w, r1.x, r1.y, r1.z, r1.w, r2.x, r2.y};

    float z1[52];
    const float4* p1r = (const float4*)(P1 + (size_t)s * PSTR);
    const float4* p2r = (const float4*)(P2 + (size_t)d * PSTR);
    #pragma unroll
    for (int i = 0; i < 13; i++) {
        float4 a = p1r[i], b = p2r[i];
        z1[4 * i]     = a.x + b.x + sb1[4 * i];
        z1[4 * i + 1] = a.y + b.y + sb1[4 * i + 1];
        z1[4 * i + 2] = a.z + b.z + sb1[4 * i + 2];
        z1[4 * i + 3] = a.w + b.w + sb1[4 * i + 3];
    }
    #pragma unroll
    for (int m2 = 0; m2 < 5; m2++) {
        float vx = ea[2 * m2], vy = ea[2 * m2 + 1];
        const float* wr0 = sW1 + (2 * m2) * 52;
        const float* wr1 = sW1 + (2 * m2 + 1) * 52;
        #pragma unroll
        for (int i = 0; i < 13; i++) {
            float4 w0 = *(const float4*)(wr0 + 4 * i);
            float4 w1v = *(const float4*)(wr1 + 4 * i);
            z1[4 * i]     += vx * w0.x + vy * w1v.x;
            z1[4 * i + 1] += vx * w0.y + vy * w1v.y;
            z1[4 * i + 2] += vx * w0.z + vy * w1v.z;
            z1[4 * i + 3] += vx * w0.w + vy * w1v.w;
        }
    }
    float z2[28];
    #pragma unroll
    for (int o = 0; o < 25; o++) z2[o] = sb2[o];
    z2[25] = z2[26] = z2[27] = 0.0f;
    #pragma unroll
    for (int k = 0; k < 50; k++) {
        float v = fmaxf(z1[k], 0.0f);
        const float* wr = sw2 + k * 28;
        #pragma unroll
        for (int i = 0; i < 7; i++) {
            float4 w = *(const float4*)(wr + 4 * i);
            z2[4 * i]     += v * w.x;
            z2[4 * i + 1] += v * w.y;
            z2[4 * i + 2] += v * w.z;
            z2[4 * i + 3] += v * w.w;
        }
    }
    float o0 = sb3[0], o1 = sb3[1];
    #pragma unroll
    for (int k = 0; k < 25; k++) {
        float v = fmaxf(z2[k], 0.0f);
        o0 += v * sw3[k * 2];
        o1 += v * sw3[k * 2 + 1];
    }
    *(float2*)(out + (size_t)eid * 2) = make_float2(o0, o1);
}

extern "C" void kernel_launch(void* const* d_in, const int* in_sizes, int n_in,
                              void* d_out, int out_size, void* d_ws, size_t ws_size,
                              hipStream_t stream) {
    const float* x         = (const float*)d_in[0];
    const float* edge_attr = (const float*)d_in[1];
    const int*   eidx      = (const int*)  d_in[2];
    const float* node_w    = (const float*)d_in[3];
    const float* node_b    = (const float*)d_in[4];
    const float* edge_w    = (const float*)d_in[5];
    const float* edge_b    = (const float*)d_in[6];
    const float* enc_w     = (const float*)d_in[7];
    const float* enc_b     = (const float*)d_in[8];
    const float* pre_w     = (const float*)d_in[9];
    const float* pre_b     = (const float*)d_in[10];
    const float* post_w    = (const float*)d_in[11];
    const float* post_b    = (const float*)d_in[12];
    const float* lin_w     = (const float*)d_in[13];
    const float* lin_b     = (const float*)d_in[14];
    const float* bn_g      = (const float*)d_in[15];
    const float* bn_b      = (const float*)d_in[16];
    const float* w1 = (const float*)d_in[17];
    const float* b1 = (const float*)d_in[18];
    const float* w2 = (const float*)d_in[19];
    const float* b2 = (const float*)d_in[20];
    const float* w3 = (const float*)d_in[21];
    const float* b3 = (const float*)d_in[22];
    const int* srcp = eidx;
    const int* dstp = eidx + NE;
    float* out = (float*)d_out;

    char* ws = (char*)d_ws;
    size_t off = 0;
    auto alloc = [&](size_t bytes) -> char* {
        char* p = ws + off;
        off += (bytes + 255) & ~(size_t)255;
        return p;
    };
    float* h      = (float*)alloc((size_t)NN * H * 4);
    float* Abuf   = (float*)alloc((size_t)NN * TF * 4);   // reused as cbuf after k_agg
    float* Bbuf   = (float*)alloc((size_t)NN * TF * 4);
    float* base   = (float*)alloc((size_t)NN * BASE_W * 4);
    float* cpre   = (float*)alloc((size_t)NN * H * 4);
    float* ea_csr = (float*)alloc((size_t)NE * REC * 4);
    float* W3e    = (float*)alloc((size_t)EFD * TF * 4);
    float* dvecF  = (float*)alloc((size_t)TF * 4);
    float* p1T    = (float*)alloc((size_t)TF * H * 4);
    float* p2T    = (float*)alloc((size_t)TF * H * 4);
    float* P1     = (float*)alloc((size_t)NN * PSTR * 4);
    float* P2     = (float*)alloc((size_t)NN * PSTR * 4);
    float* W1e    = (float*)alloc((size_t)EFD * 52 * 4);
    float* b1e    = (float*)alloc((size_t)64 * 4);
    float* amp    = (float*)alloc((size_t)NN * 4);
    float* att    = (float*)alloc((size_t)NN * 4);
    float* avgs   = (float*)alloc(256);
    float* bnz    = (float*)alloc(512);
    int* cnt_i    = (int*)alloc((size_t)NN * 4);
    int* offs     = (int*)alloc((size_t)(NN + 1) * 4);
    int* fill     = (int*)alloc((size_t)NN * 4);
    if (off > ws_size) return;

    float* cbuf = Abuf;   // safe: A dead after k_agg, cbuf dead before next k_ab

    hipMemsetAsync(cnt_i, 0, (size_t)NN * 4, stream);
    hipMemsetAsync(fill, 0, (size_t)NN * 4, stream);
    hipMemsetAsync(avgs, 0, 4, stream);

    k_deg<<<(NE + 255) / 256, 256, 0, stream>>>(dstp, cnt_i);
    k_avglog<<<64, 256, 0, stream>>>(cnt_i, avgs);
    k_ampatt<<<(NN + 255) / 256, 256, 0, stream>>>(cnt_i, avgs, amp, att);
    k_node_enc<<<(NN * H + 255) / 256, 256, 0, stream>>>(x, node_w, node_b, h);
    k_scan<<<1, 1024, 0, stream>>>(cnt_i, offs);
    k_scatter<<<(NE + 255) / 256, 256, 0, stream>>>(srcp, dstp, edge_attr, offs, fill, ea_csr);

    for (int layer = 0; layer < LAYERS; layer++) {
        k_prep1<<<(EFD * TF + TF * H + 80 + 255) / 256, 256, 0, stream>>>(
            enc_w, enc_b, edge_w, edge_b, pre_w, pre_b, W3e, dvecF, p1T, p2T, bnz, layer);
        k_ab<<<(NN + ABN - 1) / ABN, 256, 0, stream>>>(h, p1T, p2T, Abuf, Bbuf);
        k_agg<<<(NN + 3) / 4, 256, 0, stream>>>(ea_csr, Bbuf, Abuf, W3e, dvecF, cnt_i, offs, base);
        k_post<<<dim3((NN + 31) / 32, T), 256, 0, stream>>>(h, base, amp, att, post_w, post_b, cpre, layer);
        k_lin<<<(NN * H + 255) / 256, 256, 0, stream>>>(cpre, lin_w, lin_b, cbuf, layer);
        k_bnstats<<<64, 320, 0, stream>>>(cbuf, bnz, bnz + 40);
        k_bnapply<<<(NN * H + 255) / 256, 256, 0, stream>>>(cbuf, bnz, bnz + 40, bn_g, bn_b, h, layer);
    }
    k_prep2<<<(EFD * 50 + NN * 50 + 255) / 256, 256, 0, stream>>>(
        edge_w, edge_b, w1, b1, h, W1e, b1e, P1, P2);
    k_mlp<<<(NE + 255) / 256, 256, 0, stream>>>(ea_csr, P1, P2, W1e, b1e, w2, b2, w3, b3, out);
}

// Round 6
// 692.566 us; speedup vs baseline: 1.8854x; 1.0235x over previous
//
#include <hip/hip_runtime.h>
#include <hip/hip_bf16.h>
#include <cstdint>
#include <cstddef>

#define NN 25000
#define NE 400000
#define NFD 30
#define EFD 10
#define H 40
#define T 5
#define FO 8
#define LAYERS 2
#define TF 200          // T*F
#define BASE_W 800      // T*160
#define PSTR 52         // padded row stride for P1/P2
#define WS_PAD 532      // padded LDS row stride (floats) for post weights
#define ABN 64          // nodes per block in k_ab
#define REC 16          // floats per CSR edge record
#define EPSV 1e-5f

// ---------- degree histogram ----------
__global__ __launch_bounds__(256) void k_deg(const int* __restrict__ dst, int* __restrict__ cnt) {
    int e = blockIdx.x * 256 + threadIdx.x;
    if (e < NE) atomicAdd(&cnt[dst[e]], 1);
}

// ---------- sum of log(cnt+1) ----------
__global__ __launch_bounds__(256) void k_avglog(const int* __restrict__ cnt, float* __restrict__ slot) {
    __shared__ float red[256];
    float s = 0.0f;
    for (int i = blockIdx.x * 256 + threadIdx.x; i < NN; i += gridDim.x * 256)
        s += logf((float)cnt[i] + 1.0f);
    red[threadIdx.x] = s; __syncthreads();
    for (int o = 128; o > 0; o >>= 1) {
        if (threadIdx.x < o) red[threadIdx.x] += red[threadIdx.x + o];
        __syncthreads();
    }
    if (threadIdx.x == 0) atomicAdd(slot, red[0]);
}

// ---------- fused: h0 = x@node_w + node_b  AND amp/att ----------
__global__ __launch_bounds__(256) void k_node(const float* __restrict__ x, const float* __restrict__ w,
                                              const float* __restrict__ b, float* __restrict__ h,
                                              const int* __restrict__ cnt, const float* __restrict__ slot,
                                              float* __restrict__ amp, float* __restrict__ att) {
    int id = blockIdx.x * 256 + threadIdx.x;
    if (id < NN) {
        float avg = slot[0] / (float)NN;
        float c1 = fmaxf((float)cnt[id], 1.0f);
        float lg = logf(c1 + 1.0f);
        amp[id] = lg / avg;
        att[id] = avg / lg;
    }
    if (id >= NN * H) return;
    int n = id / H, j = id - n * H;
    const float* xr = x + (size_t)n * NFD;
    float acc = b[j];
    #pragma unroll
    for (int m = 0; m < NFD; m++) acc += xr[m] * w[m * H + j];
    h[id] = acc;
}

// ---------- exclusive scan of cnt -> offsets (int4-chunked, 1 block) ----------
__global__ __launch_bounds__(1024) void k_scan(const int* __restrict__ cnt, int* __restrict__ offs) {
    __shared__ int buf[1024];
    __shared__ int runbase;
    int tid = threadIdx.x;
    if (tid == 0) runbase = 0;
    __syncthreads();
    for (int base = 0; base < NN; base += 4096) {
        int i0 = base + tid * 4;
        int4 v = make_int4(0, 0, 0, 0);
        if (i0 < NN) v = *(const int4*)(cnt + i0);   // NN % 4 == 0
        int tsum = v.x + v.y + v.z + v.w;
        buf[tid] = tsum; __syncthreads();
        for (int o = 1; o < 1024; o <<= 1) {
            int t = (tid >= o) ? buf[tid - o] : 0;
            __syncthreads();
            buf[tid] += t;
            __syncthreads();
        }
        int excl = runbase + buf[tid] - tsum;
        if (i0 < NN) {
            offs[i0]     = excl;
            offs[i0 + 1] = excl + v.x;
            offs[i0 + 2] = excl + v.x + v.y;
            offs[i0 + 3] = excl + v.x + v.y + v.z;
        }
        __syncthreads();
        if (tid == 1023) runbase += buf[1023];
        __syncthreads();
    }
    if (tid == 0) offs[NN] = runbase;
}

// ---------- scatter edges into CSR records [ea0..9, src, dst, eid, 0,0,0] ----------
__global__ __launch_bounds__(256) void k_scatter(const int* __restrict__ src, const int* __restrict__ dst,
                                                 const float* __restrict__ edge_attr,
                                                 const int* __restrict__ offs, int* __restrict__ fill,
                                                 float* __restrict__ ea_csr) {
    int e = blockIdx.x * 256 + threadIdx.x;
    if (e >= NE) return;
    int d = dst[e];
    int p = offs[d] + atomicAdd(&fill[d], 1);
    const float2* ear = (const float2*)(edge_attr + (size_t)e * EFD);
    float2 v0 = ear[0], v1 = ear[1], v2 = ear[2], v3 = ear[3], v4 = ear[4];
    float4* o = (float4*)(ea_csr + (size_t)p * REC);
    o[0] = make_float4(v0.x, v0.y, v1.x, v1.y);
    o[1] = make_float4(v2.x, v2.y, v3.x, v3.y);
    o[2] = make_float4(v4.x, v4.y, __int_as_float(src[e]), __int_as_float(d));
    o[3] = make_float4(__int_as_float(e), 0.0f, 0.0f, 0.0f);
}

// ---------- per-layer prep: W3e/dvecF + p1T/p2T ----------
__global__ __launch_bounds__(256) void k_prep1(const float* __restrict__ enc_w, const float* __restrict__ enc_b,
                                               const float* __restrict__ edge_w, const float* __restrict__ edge_b,
                                               const float* __restrict__ pre_w, const float* __restrict__ pre_b,
                                               float* __restrict__ W3e, float* __restrict__ dvecF,
                                               float* __restrict__ p1T, float* __restrict__ p2T, int layer) {
    int id = blockIdx.x * 256 + threadIdx.x;
    if (id < EFD * TF) {
        int m = id / TF, j = id - m * TF;
        int t = j / H, f = j - t * H;
        const float* ew = enc_w + (size_t)layer * H * H;
        const float* pw = pre_w + (size_t)(layer * T + t) * 120 * H;
        float acc = 0.0f;
        for (int k = 0; k < H; k++) {
            float wk = edge_w[m * H + k];
            float g = 0.0f;
            #pragma unroll
            for (int o = 0; o < H; o++) g += ew[k * H + o] * pw[(80 + o) * H + f];
            acc += wk * g;
        }
        W3e[m * TF + j] = acc;
        if (m == 0) {
            const float* eb = enc_b + (size_t)layer * H;
            float dacc = pre_b[(size_t)(layer * T + t) * H + f];
            for (int o = 0; o < H; o++) {
                float ebe = eb[o];
                #pragma unroll
                for (int k = 0; k < H; k++) ebe += edge_b[k] * ew[k * H + o];
                dacc += ebe * pw[(80 + o) * H + f];
            }
            dvecF[j] = dacc;
        }
    } else if (id < EFD * TF + TF * H) {
        int id2 = id - EFD * TF;
        int j = id2 / H, m = id2 - j * H;
        int t = j / H, f = j - t * H;
        const float* pw = pre_w + (size_t)(layer * T + t) * 120 * H;
        p1T[id2] = pw[m * H + f];
        p2T[id2] = pw[(H + m) * H + f];
    }
}

// ---------- A = h@P1 (fp32), B = h@P2 (bf16) : 64-node tile in LDS ----------
__global__ __launch_bounds__(256) void k_ab(const float* __restrict__ h, const float* __restrict__ p1T,
                                            const float* __restrict__ p2T, float* __restrict__ A,
                                            __hip_bfloat16* __restrict__ Bbf) {
    __shared__ float sh[ABN * H];
    int tid = threadIdx.x;
    int n0 = blockIdx.x * ABN;
    int nodes = NN - n0; if (nodes > ABN) nodes = ABN;
    int nflt4 = nodes * H / 4;               // H%4==0
    const float4* hsrc = (const float4*)(h + (size_t)n0 * H);
    float4* sh4 = (float4*)sh;
    for (int i = tid; i < nflt4; i += 256) sh4[i] = hsrc[i];
    __syncthreads();
    int j = tid;
    if (j >= TF) return;
    float w1r[H], w2r[H];
    const float4* w1p = (const float4*)(p1T + (size_t)j * H);
    const float4* w2p = (const float4*)(p2T + (size_t)j * H);
    #pragma unroll
    for (int m4 = 0; m4 < H / 4; m4++) {
        float4 a = w1p[m4], b = w2p[m4];
        w1r[4 * m4] = a.x; w1r[4 * m4 + 1] = a.y; w1r[4 * m4 + 2] = a.z; w1r[4 * m4 + 3] = a.w;
        w2r[4 * m4] = b.x; w2r[4 * m4 + 1] = b.y; w2r[4 * m4 + 2] = b.z; w2r[4 * m4 + 3] = b.w;
    }
    for (int n = 0; n < nodes; n++) {
        const float4* hr = (const float4*)(sh + n * H);
        float a = 0.0f, b = 0.0f;
        #pragma unroll
        for (int m4 = 0; m4 < H / 4; m4++) {
            float4 hv = hr[m4];                       // same addr all lanes -> LDS broadcast
            a += hv.x * w1r[4 * m4]     + hv.y * w1r[4 * m4 + 1]
               + hv.z * w1r[4 * m4 + 2] + hv.w * w1r[4 * m4 + 3];
            b += hv.x * w2r[4 * m4]     + hv.y * w2r[4 * m4 + 1]
               + hv.z * w2r[4 * m4 + 2] + hv.w * w2r[4 * m4 + 3];
        }
        size_t o = (size_t)(n0 + n) * TF + j;         // lanes j consecutive -> coalesced
        A[o] = a;
        Bbf[o] = __float2bfloat16(b);
    }
}

// ---------- aggregation: wave per node, scalar CSR-record loads, bf16 B-gather ----------
__global__ __launch_bounds__(256) void k_agg(const float* __restrict__ ea_csr,
                                             const __hip_bfloat16* __restrict__ Bbf,
                                             const float* __restrict__ A, const float* __restrict__ w3e,
                                             const float* __restrict__ dvecF, const int* __restrict__ cnt,
                                             const int* __restrict__ offs, float* __restrict__ base) {
    int tid = threadIdx.x;
    int lane = tid & 63;
    int n = __builtin_amdgcn_readfirstlane((int)(blockIdx.x * 4 + (tid >> 6)));   // NN%4==0
    int deg = cnt[n];          // uniform -> s_load
    int start = offs[n];       // uniform -> s_load
    bool comp = lane < TF / 4; // lanes 0..49
    float4 w3q[EFD];
    float4 dj4 = make_float4(0, 0, 0, 0), a4 = make_float4(0, 0, 0, 0);
    if (comp) {
        #pragma unroll
        for (int m = 0; m < EFD; m++) w3q[m] = *(const float4*)(w3e + m * TF + 4 * lane);
        dj4 = *(const float4*)(dvecF + 4 * lane);
        a4  = *(const float4*)(A + (size_t)n * TF + 4 * lane);
    }
    float sx = 0, sy = 0, sz = 0, sw_ = 0;
    float qx = 0, qy = 0, qz = 0, qw = 0;
    float mnx = 3.4e38f, mny = 3.4e38f, mnz = 3.4e38f, mnw = 3.4e38f;
    float mxx = -3.4e38f, mxy = -3.4e38f, mxz = -3.4e38f, mxw = -3.4e38f;
    const float4* recbase = (const float4*)ea_csr + (size_t)start * 4;
    const uint16_t* Bu = (const uint16_t*)Bbf;
    #pragma unroll 2
    for (int r = 0; r < deg; r++) {
        float4 qa = recbase[r * 4];        // uniform addr -> scalar path
        float4 qb = recbase[r * 4 + 1];
        float4 qc = recbase[r * 4 + 2];
        int sn = __float_as_int(qc.z);
        if (comp) {
            uint2 bv = *(const uint2*)(Bu + (size_t)sn * TF + 4 * lane);   // 8 B bf16x4
            float b0 = __uint_as_float(bv.x << 16);
            float b1 = __uint_as_float(bv.x & 0xffff0000u);
            float b2 = __uint_as_float(bv.y << 16);
            float b3 = __uint_as_float(bv.y & 0xffff0000u);
            float eav[EFD] = {qa.x, qa.y, qa.z, qa.w, qb.x, qb.y, qb.z, qb.w, qc.x, qc.y};
            float cx = dj4.x, cy = dj4.y, cz = dj4.z, cw = dj4.w;
            #pragma unroll
            for (int m = 0; m < EFD; m++) {
                cx = fmaf(eav[m], w3q[m].x, cx);
                cy = fmaf(eav[m], w3q[m].y, cy);
                cz = fmaf(eav[m], w3q[m].z, cz);
                cw = fmaf(eav[m], w3q[m].w, cw);
            }
            float ux = b0 + cx, uy = b1 + cy, uz = b2 + cz, uw = b3 + cw;
            sx += ux; qx = fmaf(ux, ux, qx); mnx = fminf(mnx, ux); mxx = fmaxf(mxx, ux);
            sy += uy; qy = fmaf(uy, uy, qy); mny = fminf(mny, uy); mxy = fmaxf(mxy, uy);
            sz += uz; qz = fmaf(uz, uz, qz); mnz = fminf(mnz, uz); mxz = fmaxf(mxz, uz);
            sw_ += uw; qw = fmaf(uw, uw, qw); mnw = fminf(mnw, uw); mxw = fmaxf(mxw, uw);
        }
    }
    if (comp) {
        float d = (float)deg, c1 = fmaxf(d, 1.0f);
        float inv = 1.0f / c1;
        float mex = (d * a4.x + sx) * inv, mey = (d * a4.y + sy) * inv;
        float mez = (d * a4.z + sz) * inv, mew = (d * a4.w + sw_) * inv;
        float msx = (d * a4.x * a4.x + 2.0f * a4.x * sx + qx) * inv;
        float msy = (d * a4.y * a4.y + 2.0f * a4.y * sy + qy) * inv;
        float msz = (d * a4.z * a4.z + 2.0f * a4.z * sz + qz) * inv;
        float msw = (d * a4.w * a4.w + 2.0f * a4.w * sw_ + qw) * inv;
        float4 mean4 = make_float4(mex, mey, mez, mew);
        float4 sd4 = make_float4(sqrtf(fmaxf(msx - mex * mex, 0.0f) + EPSV),
                                 sqrtf(fmaxf(msy - mey * mey, 0.0f) + EPSV),
                                 sqrtf(fmaxf(msz - mez * mez, 0.0f) + EPSV),
                                 sqrtf(fmaxf(msw - mew * mew, 0.0f) + EPSV));
        bool has = deg > 0;
        float4 mnv4 = has ? make_float4(a4.x + mnx, a4.y + mny, a4.z + mnz, a4.w + mnw)
                          : make_float4(0, 0, 0, 0);
        float4 mxv4 = has ? make_float4(a4.x + mxx, a4.y + mxy, a4.z + mxz, a4.w + mxw)
                          : make_float4(0, 0, 0, 0);
        int j0 = 4 * lane;
        int t = j0 / H, f = j0 - t * H;
        float* bb = base + (size_t)n * BASE_W + t * 160 + f;
        *(float4*)(bb)       = mean4;
        *(float4*)(bb + 40)  = mnv4;
        *(float4*)(bb + 80)  = mxv4;
        *(float4*)(bb + 120) = sd4;
    }
}

// ---------- post einsum, t-split: block = 32 nodes x 8 outputs, weight slice in LDS ----------
__global__ __launch_bounds__(256) void k_post(const float* __restrict__ h, const float* __restrict__ base,
                                              const float* __restrict__ amp, const float* __restrict__ att,
                                              const float* __restrict__ post_w, const float* __restrict__ post_b,
                                              float* __restrict__ cpre, int layer) {
    __shared__ float ws[FO * WS_PAD];
    int tid = threadIdx.x;
    int t = blockIdx.y;
    const float* pwsrc = post_w + (size_t)(layer * T + t) * 520 * FO;
    for (int i = tid; i < 520 * FO; i += 256) {
        int g = i >> 3, o = i & 7;
        ws[o * WS_PAD + g] = pwsrc[i];
    }
    __syncthreads();
    int nl = tid >> 3, o = tid & 7;
    int n = blockIdx.x * 32 + nl;
    if (n >= NN) return;
    const float* wrow = ws + o * WS_PAD;
    float am = amp[n], at = att[n];
    float acc = post_b[(size_t)(layer * T + t) * FO + o];
    const float4* hx = (const float4*)(h + (size_t)n * H);
    #pragma unroll
    for (int g4 = 0; g4 < 10; g4++) {
        float4 xv = hx[g4];
        float4 wv = *(const float4*)(wrow + g4 * 4);
        acc += xv.x * wv.x + xv.y * wv.y + xv.z * wv.z + xv.w * wv.w;
    }
    const float4* br = (const float4*)(base + (size_t)n * BASE_W + t * 160);
    #pragma unroll
    for (int g4 = 0; g4 < 40; g4++) {
        float4 bv = br[g4];
        float4 wa = *(const float4*)(wrow + 40 + g4 * 4);
        float4 wb = *(const float4*)(wrow + 200 + g4 * 4);
        float4 wc = *(const float4*)(wrow + 360 + g4 * 4);
        acc += bv.x * (wa.x + am * wb.x + at * wc.x);
        acc += bv.y * (wa.y + am * wb.y + at * wc.y);
        acc += bv.z * (wa.z + am * wb.z + at * wc.z);
        acc += bv.w * (wa.w + am * wb.w + at * wc.w);
    }
    cpre[(size_t)n * H + t * FO + o] = acc;
}

// ---------- fused lin + BN-stats: 6 nodes per block-iter, register accumulation ----------
__global__ __launch_bounds__(256) void k_linbn(const float* __restrict__ cpre, const float* __restrict__ lin_w,
                                               const float* __restrict__ lin_b, float* __restrict__ cbuf,
                                               float* __restrict__ bnsum, float* __restrict__ bnsq, int layer) {
    __shared__ float scp[240];
    __shared__ float red[80];
    int tid = threadIdx.x;
    int j = tid % H, nl = tid / H;      // nl 0..6 (tid 240..255 idle for compute)
    const float* lw = lin_w + (size_t)layer * H * H;
    float wcol[H];
    #pragma unroll
    for (int k = 0; k < H; k++) wcol[k] = lw[k * H + j];
    float lb = lin_b[(size_t)layer * H + j];
    float lsum = 0.0f, lsq = 0.0f;
    for (int n0 = blockIdx.x * 6; n0 < NN; n0 += gridDim.x * 6) {
        int nn = NN - n0; if (nn > 6) nn = 6;
        if (tid < nn * H) scp[tid] = cpre[(size_t)n0 * H + tid];
        __syncthreads();
        if (nl < nn) {
            float acc = lb;
            #pragma unroll
            for (int k = 0; k < H; k++) acc += scp[nl * H + k] * wcol[k];
            cbuf[(size_t)(n0 + nl) * H + j] = acc;
            lsum += acc; lsq += acc * acc;
        }
        __syncthreads();
    }
    if (tid < 80) red[tid] = 0.0f;
    __syncthreads();
    if (nl < 6) { atomicAdd(&red[j], lsum); atomicAdd(&red[40 + j], lsq); }
    __syncthreads();
    if (tid < 40) atomicAdd(&bnsum[tid], red[tid]);
    else if (tid < 80) atomicAdd(&bnsq[tid - 40], red[tid]);
}

// ---------- BN apply + residual ----------
__global__ __launch_bounds__(256) void k_bnapply(const float* __restrict__ cbuf, const float* __restrict__ bnsum,
                                                 const float* __restrict__ bnsq, const float* __restrict__ bn_g,
                                                 const float* __restrict__ bn_b, float* __restrict__ h, int layer) {
    int id = blockIdx.x * 256 + threadIdx.x;
    if (id >= NN * H) return;
    int j = id % H;
    float mu = bnsum[j] / (float)NN;
    float var = bnsq[j] / (float)NN - mu * mu;
    float inv = rsqrtf(var + EPSV);
    float cv = (cbuf[id] - mu) * inv * bn_g[(size_t)layer * H + j] + bn_b[(size_t)layer * H + j];
    h[id] = (h[id] + fmaxf(cv, 0.0f)) * 0.5f;
}

// ---------- final prep: W1e/b1e fold + P1/P2 node partials ----------
__global__ __launch_bounds__(256) void k_prep2(const float* __restrict__ edge_w, const float* __restrict__ edge_b,
                                               const float* __restrict__ w1, const float* __restrict__ b1,
                                               const float* __restrict__ h,
                                               float* __restrict__ W1e, float* __restrict__ b1e,
                                               float* __restrict__ P1, float* __restrict__ P2) {
    int id = blockIdx.x * 256 + threadIdx.x;
    if (id < EFD * 50) {
        int m = id / 50, o = id - m * 50;
        float acc = 0.0f;
        #pragma unroll
        for (int k = 0; k < H; k++) acc += edge_w[m * H + k] * w1[(80 + k) * 50 + o];
        W1e[m * 50 + o] = acc;
        if (m == 0) {
            float bacc = b1[o];
            #pragma unroll
            for (int k = 0; k < H; k++) bacc += edge_b[k] * w1[(80 + k) * 50 + o];
            b1e[o] = bacc;
        }
    } else if (id < EFD * 50 + NN * 50) {
        int id2 = id - EFD * 50;
        int n = id2 / 50, o = id2 - n * 50;
        const float* hr = h + (size_t)n * H;
        float a1 = 0.0f, a2 = 0.0f;
        #pragma unroll
        for (int f = 0; f < H; f++) {
            float v = fmaxf(hr[f], 0.0f);
            a1 += v * w1[f * 50 + o];
            a2 += v * w1[(H + f) * 50 + o];
        }
        P1[(size_t)n * PSTR + o] = a1;
        P2[(size_t)n * PSTR + o] = a2;
    }
}

// ---------- final edge MLP: all weights via uniform scalar loads (no LDS) ----------
__global__ __launch_bounds__(256) void k_mlp(const float* __restrict__ ea_csr, const float* __restrict__ P1,
                                             const float* __restrict__ P2, const float* __restrict__ W1e,
                                             const float* __restrict__ b1e, const float* __restrict__ w2,
                                             const float* __restrict__ b2, const float* __restrict__ w3,
                                             const float* __restrict__ b3, float* __restrict__ out) {
    int p = blockIdx.x * 256 + threadIdx.x;
    if (p >= NE) return;
    const float4* rec = (const float4*)ea_csr + (size_t)p * 4;
    float4 r0 = rec[0], r1 = rec[1], r2 = rec[2], r3 = rec[3];
    int s = __float_as_int(r2.z), d = __float_as_int(r2.w), eid = __float_as_int(r3.x);
    float ea[EFD] = {r0.x, r0.y, r0.z, r0.w, r1.x, r1.y, r1.z, r1.w, r2.x, r2.y};

    float z1[52];
    const float4* p1r = (const float4*)(P1 + (size_t)s * PSTR);
    const float4* p2r = (const float4*)(P2 + (size_t)d * PSTR);
    #pragma unroll
    for (int i = 0; i < 13; i++) {
        float4 a = p1r[i], b = p2r[i];
        z1[4 * i]     = a.x + b.x;
        z1[4 * i + 1] = a.y + b.y;
        z1[4 * i + 2] = a.z + b.z;
        z1[4 * i + 3] = a.w + b.w;
    }
    #pragma unroll
    for (int k = 0; k < 50; k++) z1[k] += b1e[k];              // uniform -> scalar
    #pragma unroll
    for (int m = 0; m < EFD; m++) {
        float v = ea[m];
        #pragma unroll
        for (int k = 0; k < 50; k++) z1[k] = fmaf(v, W1e[m * 50 + k], z1[k]);   // scalar weights
    }
    float z2[25];
    #pragma unroll
    for (int o = 0; o < 25; o++) z2[o] = b2[o];
    #pragma unroll
    for (int k = 0; k < 50; k++) {
        float v = fmaxf(z1[k], 0.0f);
        #pragma unroll
        for (int o = 0; o < 25; o++) z2[o] = fmaf(v, w2[k * 25 + o], z2[o]);    // scalar weights
    }
    float o0 = b3[0], o1 = b3[1];
    #pragma unroll
    for (int k = 0; k < 25; k++) {
        float v = fmaxf(z2[k], 0.0f);
        o0 = fmaf(v, w3[k * 2], o0);
        o1 = fmaf(v, w3[k * 2 + 1], o1);
    }
    *(float2*)(out + (size_t)eid * 2) = make_float2(o0, o1);
}

extern "C" void kernel_launch(void* const* d_in, const int* in_sizes, int n_in,
                              void* d_out, int out_size, void* d_ws, size_t ws_size,
                              hipStream_t stream) {
    const float* x         = (const float*)d_in[0];
    const float* edge_attr = (const float*)d_in[1];
    const int*   eidx      = (const int*)  d_in[2];
    const float* node_w    = (const float*)d_in[3];
    const float* node_b    = (const float*)d_in[4];
    const float* edge_w    = (const float*)d_in[5];
    const float* edge_b    = (const float*)d_in[6];
    const float* enc_w     = (const float*)d_in[7];
    const float* enc_b     = (const float*)d_in[8];
    const float* pre_w     = (const float*)d_in[9];
    const float* pre_b     = (const float*)d_in[10];
    const float* post_w    = (const float*)d_in[11];
    const float* post_b    = (const float*)d_in[12];
    const float* lin_w     = (const float*)d_in[13];
    const float* lin_b     = (const float*)d_in[14];
    const float* bn_g      = (const float*)d_in[15];
    const float* bn_b      = (const float*)d_in[16];
    const float* w1 = (const float*)d_in[17];
    const float* b1 = (const float*)d_in[18];
    const float* w2 = (const float*)d_in[19];
    const float* b2 = (const float*)d_in[20];
    const float* w3 = (const float*)d_in[21];
    const float* b3 = (const float*)d_in[22];
    const int* srcp = eidx;
    const int* dstp = eidx + NE;
    float* out = (float*)d_out;

    char* ws = (char*)d_ws;
    size_t off = 0;
    auto alloc = [&](size_t bytes) -> char* {
        char* p = ws + off;
        off += (bytes + 255) & ~(size_t)255;
        return p;
    };
    float* h      = (float*)alloc((size_t)NN * H * 4);
    float* Abuf   = (float*)alloc((size_t)NN * TF * 4);   // reused as cbuf after k_agg
    __hip_bfloat16* Bbf = (__hip_bfloat16*)alloc((size_t)NN * TF * 2 + 256);
    float* base   = (float*)alloc((size_t)NN * BASE_W * 4);
    float* cpre   = (float*)alloc((size_t)NN * H * 4);
    float* ea_csr = (float*)alloc((size_t)NE * REC * 4);
    float* W3e    = (float*)alloc((size_t)EFD * TF * 4);
    float* dvecF  = (float*)alloc((size_t)TF * 4);
    float* p1T    = (float*)alloc((size_t)TF * H * 4);
    float* p2T    = (float*)alloc((size_t)TF * H * 4);
    float* P1     = (float*)alloc((size_t)NN * PSTR * 4);
    float* P2     = (float*)alloc((size_t)NN * PSTR * 4);
    float* W1e    = (float*)alloc((size_t)EFD * 50 * 4);
    float* b1e    = (float*)alloc((size_t)64 * 4);
    float* amp    = (float*)alloc((size_t)NN * 4);
    float* att    = (float*)alloc((size_t)NN * 4);
    int* offs     = (int*)alloc((size_t)(NN + 1) * 4);
    // ---- contiguous zero region: cnt, fill, avgs, bnz(2 layers) ----
    size_t zoff = off;
    int* cnt_i    = (int*)alloc((size_t)NN * 4);
    int* fill     = (int*)alloc((size_t)NN * 4);
    float* avgs   = (float*)alloc(256);
    float* bnz    = (float*)alloc(1024);   // layer l: bnz + l*128 floats (sum 40 | sq 40)
    size_t zsize = off - zoff;
    if (off > ws_size) return;

    float* cbuf = Abuf;   // safe: A dead after k_agg, cbuf dead before next k_ab

    hipMemsetAsync(cnt_i, 0, zsize, stream);

    k_deg<<<(NE + 255) / 256, 256, 0, stream>>>(dstp, cnt_i);
    k_avglog<<<64, 256, 0, stream>>>(cnt_i, avgs);
    k_node<<<(NN * H + 255) / 256, 256, 0, stream>>>(x, node_w, node_b, h, cnt_i, avgs, amp, att);
    k_scan<<<1, 1024, 0, stream>>>(cnt_i, offs);
    k_scatter<<<(NE + 255) / 256, 256, 0, stream>>>(srcp, dstp, edge_attr, offs, fill, ea_csr);

    for (int layer = 0; layer < LAYERS; layer++) {
        float* bnzL = bnz + layer * 128;
        k_prep1<<<(EFD * TF + TF * H + 255) / 256, 256, 0, stream>>>(
            enc_w, enc_b, edge_w, edge_b, pre_w, pre_b, W3e, dvecF, p1T, p2T, layer);
        k_ab<<<(NN + ABN - 1) / ABN, 256, 0, stream>>>(h, p1T, p2T, Abuf, Bbf);
        k_agg<<<NN / 4, 256, 0, stream>>>(ea_csr, Bbf, Abuf, W3e, dvecF, cnt_i, offs, base);
        k_post<<<dim3((NN + 31) / 32, T), 256, 0, stream>>>(h, base, amp, att, post_w, post_b, cpre, layer);
        k_linbn<<<1024, 256, 0, stream>>>(cpre, lin_w, lin_b, cbuf, bnzL, bnzL + 40, layer);
        k_bnapply<<<(NN * H + 255) / 256, 256, 0, stream>>>(cbuf, bnzL, bnzL + 40, bn_g, bn_b, h, layer);
    }
    k_prep2<<<(EFD * 50 + NN * 50 + 255) / 256, 256, 0, stream>>>(
        edge_w, edge_b, w1, b1, h, W1e, b1e, P1, P2);
    k_mlp<<<(NE + 255) / 256, 256, 0, stream>>>(ea_csr, P1, P2, W1e, b1e, w2, b2, w3, b3, out);
}

// Round 7
// 646.419 us; speedup vs baseline: 2.0200x; 1.0714x over previous
//
#include <hip/hip_runtime.h>
#include <hip/hip_bf16.h>
#include <cstdint>
#include <cstddef>

#define NN 25000
#define NE 400000
#define NFD 30
#define EFD 10
#define H 40
#define T 5
#define FO 8
#define LAYERS 2
#define TF 200          // T*F
#define BASE_W 800      // T*160
#define PSTR 52         // padded row stride for P1/P2
#define WS_PAD 532      // padded LDS row stride (floats) for post weights
#define ABN 64          // nodes per block in k_ab
#define REC 16          // floats per CSR edge record
#define EPSV 1e-5f

// ---------- degree histogram ----------
__global__ __launch_bounds__(256) void k_deg(const int* __restrict__ dst, int* __restrict__ cnt) {
    int e = blockIdx.x * 256 + threadIdx.x;
    if (e < NE) atomicAdd(&cnt[dst[e]], 1);
}

// ---------- sum of log(cnt+1) ----------
__global__ __launch_bounds__(256) void k_avglog(const int* __restrict__ cnt, float* __restrict__ slot) {
    __shared__ float red[256];
    float s = 0.0f;
    for (int i = blockIdx.x * 256 + threadIdx.x; i < NN; i += gridDim.x * 256)
        s += logf((float)cnt[i] + 1.0f);
    red[threadIdx.x] = s; __syncthreads();
    for (int o = 128; o > 0; o >>= 1) {
        if (threadIdx.x < o) red[threadIdx.x] += red[threadIdx.x + o];
        __syncthreads();
    }
    if (threadIdx.x == 0) atomicAdd(slot, red[0]);
}

// ---------- fused: h0 = x@node_w + node_b  AND amp/att ----------
__global__ __launch_bounds__(256) void k_node(const float* __restrict__ x, const float* __restrict__ w,
                                              const float* __restrict__ b, float* __restrict__ h,
                                              const int* __restrict__ cnt, const float* __restrict__ slot,
                                              float* __restrict__ amp, float* __restrict__ att) {
    int id = blockIdx.x * 256 + threadIdx.x;
    if (id < NN) {
        float avg = slot[0] / (float)NN;
        float c1 = fmaxf((float)cnt[id], 1.0f);
        float lg = logf(c1 + 1.0f);
        amp[id] = lg / avg;
        att[id] = avg / lg;
    }
    if (id >= NN * H) return;
    int n = id / H, j = id - n * H;
    const float* xr = x + (size_t)n * NFD;
    float acc = b[j];
    #pragma unroll
    for (int m = 0; m < NFD; m++) acc += xr[m] * w[m * H + j];
    h[id] = acc;
}

// ---------- exclusive scan of cnt -> offsets (shfl-based, 1 block, 3 barriers/chunk) ----------
__global__ __launch_bounds__(1024) void k_scan(const int* __restrict__ cnt, int* __restrict__ offs) {
    __shared__ int wsum[16];
    int tid = threadIdx.x;
    int lane = tid & 63, wv = tid >> 6;
    int runbase = 0;
    for (int base = 0; base < NN; base += 4096) {
        int i0 = base + tid * 4;
        int4 v = make_int4(0, 0, 0, 0);
        if (i0 < NN) v = *(const int4*)(cnt + i0);   // NN % 4 == 0
        int tsum = v.x + v.y + v.z + v.w;
        // wave inclusive scan
        int x = tsum;
        #pragma unroll
        for (int o = 1; o < 64; o <<= 1) {
            int y = __shfl_up(x, o);
            if (lane >= o) x += y;
        }
        if (lane == 63) wsum[wv] = x;
        __syncthreads();
        if (wv == 0 && lane < 16) {
            int wsv = wsum[lane];
            #pragma unroll
            for (int o = 1; o < 16; o <<= 1) {
                int y = __shfl_up(wsv, o);
                if (lane >= o) wsv += y;
            }
            wsum[lane] = wsv;
        }
        __syncthreads();
        int wpref = (wv > 0) ? wsum[wv - 1] : 0;
        int excl = runbase + wpref + x - tsum;
        if (i0 < NN) {
            offs[i0]     = excl;
            offs[i0 + 1] = excl + v.x;
            offs[i0 + 2] = excl + v.x + v.y;
            offs[i0 + 3] = excl + v.x + v.y + v.z;
        }
        runbase += wsum[15];
        __syncthreads();   // protect wsum before next-iter overwrite
    }
    if (tid == 0) offs[NN] = runbase;
}

// ---------- scatter edges into CSR records [ea0..9, src, dst, eid, 0,0,0] ----------
__global__ __launch_bounds__(256) void k_scatter(const int* __restrict__ src, const int* __restrict__ dst,
                                                 const float* __restrict__ edge_attr,
                                                 const int* __restrict__ offs, int* __restrict__ fill,
                                                 float* __restrict__ ea_csr) {
    int e = blockIdx.x * 256 + threadIdx.x;
    if (e >= NE) return;
    int d = dst[e];
    int p = offs[d] + atomicAdd(&fill[d], 1);
    const float2* ear = (const float2*)(edge_attr + (size_t)e * EFD);
    float2 v0 = ear[0], v1 = ear[1], v2 = ear[2], v3 = ear[3], v4 = ear[4];
    float4* o = (float4*)(ea_csr + (size_t)p * REC);
    o[0] = make_float4(v0.x, v0.y, v1.x, v1.y);
    o[1] = make_float4(v2.x, v2.y, v3.x, v3.y);
    o[2] = make_float4(v4.x, v4.y, __int_as_float(src[e]), __int_as_float(d));
    o[3] = make_float4(__int_as_float(e), 0.0f, 0.0f, 0.0f);
}

// ---------- per-layer prep: W3e/dvecF + p1T/p2T ----------
__global__ __launch_bounds__(256) void k_prep1(const float* __restrict__ enc_w, const float* __restrict__ enc_b,
                                               const float* __restrict__ edge_w, const float* __restrict__ edge_b,
                                               const float* __restrict__ pre_w, const float* __restrict__ pre_b,
                                               float* __restrict__ W3e, float* __restrict__ dvecF,
                                               float* __restrict__ p1T, float* __restrict__ p2T, int layer) {
    int id = blockIdx.x * 256 + threadIdx.x;
    if (id < EFD * TF) {
        int m = id / TF, j = id - m * TF;
        int t = j / H, f = j - t * H;
        const float* ew = enc_w + (size_t)layer * H * H;
        const float* pw = pre_w + (size_t)(layer * T + t) * 120 * H;
        float acc = 0.0f;
        for (int k = 0; k < H; k++) {
            float wk = edge_w[m * H + k];
            float g = 0.0f;
            #pragma unroll
            for (int o = 0; o < H; o++) g += ew[k * H + o] * pw[(80 + o) * H + f];
            acc += wk * g;
        }
        W3e[m * TF + j] = acc;
        if (m == 0) {
            const float* eb = enc_b + (size_t)layer * H;
            float dacc = pre_b[(size_t)(layer * T + t) * H + f];
            for (int o = 0; o < H; o++) {
                float ebe = eb[o];
                #pragma unroll
                for (int k = 0; k < H; k++) ebe += edge_b[k] * ew[k * H + o];
                dacc += ebe * pw[(80 + o) * H + f];
            }
            dvecF[j] = dacc;
        }
    } else if (id < EFD * TF + TF * H) {
        int id2 = id - EFD * TF;
        int j = id2 / H, m = id2 - j * H;
        int t = j / H, f = j - t * H;
        const float* pw = pre_w + (size_t)(layer * T + t) * 120 * H;
        p1T[id2] = pw[m * H + f];
        p2T[id2] = pw[(H + m) * H + f];
    }
}

// ---------- A = h@P1 (fp32), B = h@P2 (bf16) : 64-node tile in LDS ----------
__global__ __launch_bounds__(256) void k_ab(const float* __restrict__ h, const float* __restrict__ p1T,
                                            const float* __restrict__ p2T, float* __restrict__ A,
                                            __hip_bfloat16* __restrict__ Bbf) {
    __shared__ float sh[ABN * H];
    int tid = threadIdx.x;
    int n0 = blockIdx.x * ABN;
    int nodes = NN - n0; if (nodes > ABN) nodes = ABN;
    int nflt4 = nodes * H / 4;               // H%4==0
    const float4* hsrc = (const float4*)(h + (size_t)n0 * H);
    float4* sh4 = (float4*)sh;
    for (int i = tid; i < nflt4; i += 256) sh4[i] = hsrc[i];
    __syncthreads();
    int j = tid;
    if (j >= TF) return;
    float w1r[H], w2r[H];
    const float4* w1p = (const float4*)(p1T + (size_t)j * H);
    const float4* w2p = (const float4*)(p2T + (size_t)j * H);
    #pragma unroll
    for (int m4 = 0; m4 < H / 4; m4++) {
        float4 a = w1p[m4], b = w2p[m4];
        w1r[4 * m4] = a.x; w1r[4 * m4 + 1] = a.y; w1r[4 * m4 + 2] = a.z; w1r[4 * m4 + 3] = a.w;
        w2r[4 * m4] = b.x; w2r[4 * m4 + 1] = b.y; w2r[4 * m4 + 2] = b.z; w2r[4 * m4 + 3] = b.w;
    }
    for (int n = 0; n < nodes; n++) {
        const float4* hr = (const float4*)(sh + n * H);
        float a = 0.0f, b = 0.0f;
        #pragma unroll
        for (int m4 = 0; m4 < H / 4; m4++) {
            float4 hv = hr[m4];                       // same addr all lanes -> LDS broadcast
            a += hv.x * w1r[4 * m4]     + hv.y * w1r[4 * m4 + 1]
               + hv.z * w1r[4 * m4 + 2] + hv.w * w1r[4 * m4 + 3];
            b += hv.x * w2r[4 * m4]     + hv.y * w2r[4 * m4 + 1]
               + hv.z * w2r[4 * m4 + 2] + hv.w * w2r[4 * m4 + 3];
        }
        size_t o = (size_t)(n0 + n) * TF + j;         // lanes j consecutive -> coalesced
        A[o] = a;
        Bbf[o] = __float2bfloat16(b);
    }
}

// ---------- aggregation: wave per node, 4-deep pipelined scalar records + bf16 B-gathers ----------
__global__ __launch_bounds__(256) void k_agg(const float* __restrict__ ea_csr,
                                             const __hip_bfloat16* __restrict__ Bbf,
                                             const float* __restrict__ A, const float* __restrict__ w3e,
                                             const float* __restrict__ dvecF, const int* __restrict__ cnt,
                                             const int* __restrict__ offs, float* __restrict__ base) {
    int tid = threadIdx.x;
    int lane = tid & 63;
    int n = __builtin_amdgcn_readfirstlane((int)(blockIdx.x * 4 + (tid >> 6)));   // NN%4==0
    int deg = cnt[n];          // uniform -> s_load
    int start = offs[n];       // uniform -> s_load
    bool comp = lane < TF / 4; // lanes 0..49
    float4 w3q[EFD];
    float4 dj4 = make_float4(0, 0, 0, 0), a4 = make_float4(0, 0, 0, 0);
    if (comp) {
        #pragma unroll
        for (int m = 0; m < EFD; m++) w3q[m] = *(const float4*)(w3e + m * TF + 4 * lane);
        dj4 = *(const float4*)(dvecF + 4 * lane);
        a4  = *(const float4*)(A + (size_t)n * TF + 4 * lane);
    }
    float sx = 0, sy = 0, sz = 0, sw_ = 0;
    float qx = 0, qy = 0, qz = 0, qw = 0;
    float mnx = 3.4e38f, mny = 3.4e38f, mnz = 3.4e38f, mnw = 3.4e38f;
    float mxx = -3.4e38f, mxy = -3.4e38f, mxz = -3.4e38f, mxw = -3.4e38f;
    const float4* recb = (const float4*)ea_csr + (size_t)start * 4;
    const uint16_t* Bu = (const uint16_t*)Bbf;

    auto edge = [&](float4 qa, float4 qb, float4 qc, uint2 bv) {
        float b0 = __uint_as_float(bv.x << 16);
        float b1 = __uint_as_float(bv.x & 0xffff0000u);
        float b2 = __uint_as_float(bv.y << 16);
        float b3 = __uint_as_float(bv.y & 0xffff0000u);
        float eav[EFD] = {qa.x, qa.y, qa.z, qa.w, qb.x, qb.y, qb.z, qb.w, qc.x, qc.y};
        float cx = dj4.x, cy = dj4.y, cz = dj4.z, cw = dj4.w;
        #pragma unroll
        for (int m = 0; m < EFD; m++) {
            cx = fmaf(eav[m], w3q[m].x, cx);
            cy = fmaf(eav[m], w3q[m].y, cy);
            cz = fmaf(eav[m], w3q[m].z, cz);
            cw = fmaf(eav[m], w3q[m].w, cw);
        }
        float ux = b0 + cx, uy = b1 + cy, uz = b2 + cz, uw = b3 + cw;
        sx += ux; qx = fmaf(ux, ux, qx); mnx = fminf(mnx, ux); mxx = fmaxf(mxx, ux);
        sy += uy; qy = fmaf(uy, uy, qy); mny = fminf(mny, uy); mxy = fmaxf(mxy, uy);
        sz += uz; qz = fmaf(uz, uz, qz); mnz = fminf(mnz, uz); mxz = fmaxf(mxz, uz);
        sw_ += uw; qw = fmaf(uw, uw, qw); mnw = fminf(mnw, uw); mxw = fmaxf(mxw, uw);
    };

    int r = 0;
    for (; r + 4 <= deg; r += 4) {
        // batch scalar record loads (uniform)
        float4 qa0 = recb[(r + 0) * 4], qb0 = recb[(r + 0) * 4 + 1], qc0 = recb[(r + 0) * 4 + 2];
        float4 qa1 = recb[(r + 1) * 4], qb1 = recb[(r + 1) * 4 + 1], qc1 = recb[(r + 1) * 4 + 2];
        float4 qa2 = recb[(r + 2) * 4], qb2 = recb[(r + 2) * 4 + 1], qc2 = recb[(r + 2) * 4 + 2];
        float4 qa3 = recb[(r + 3) * 4], qb3 = recb[(r + 3) * 4 + 1], qc3 = recb[(r + 3) * 4 + 2];
        int s0 = __float_as_int(qc0.z), s1 = __float_as_int(qc1.z);
        int s2 = __float_as_int(qc2.z), s3 = __float_as_int(qc3.z);
        if (comp) {
            // 4 outstanding gathers before any use
            uint2 v0 = *(const uint2*)(Bu + (size_t)s0 * TF + 4 * lane);
            uint2 v1 = *(const uint2*)(Bu + (size_t)s1 * TF + 4 * lane);
            uint2 v2 = *(const uint2*)(Bu + (size_t)s2 * TF + 4 * lane);
            uint2 v3 = *(const uint2*)(Bu + (size_t)s3 * TF + 4 * lane);
            edge(qa0, qb0, qc0, v0);
            edge(qa1, qb1, qc1, v1);
            edge(qa2, qb2, qc2, v2);
            edge(qa3, qb3, qc3, v3);
        }
    }
    for (; r < deg; r++) {
        float4 qa = recb[r * 4], qb = recb[r * 4 + 1], qc = recb[r * 4 + 2];
        int sn = __float_as_int(qc.z);
        if (comp) {
            uint2 bv = *(const uint2*)(Bu + (size_t)sn * TF + 4 * lane);
            edge(qa, qb, qc, bv);
        }
    }
    if (comp) {
        float d = (float)deg, c1 = fmaxf(d, 1.0f);
        float inv = 1.0f / c1;
        float mex = (d * a4.x + sx) * inv, mey = (d * a4.y + sy) * inv;
        float mez = (d * a4.z + sz) * inv, mew = (d * a4.w + sw_) * inv;
        float msx = (d * a4.x * a4.x + 2.0f * a4.x * sx + qx) * inv;
        float msy = (d * a4.y * a4.y + 2.0f * a4.y * sy + qy) * inv;
        float msz = (d * a4.z * a4.z + 2.0f * a4.z * sz + qz) * inv;
        float msw = (d * a4.w * a4.w + 2.0f * a4.w * sw_ + qw) * inv;
        float4 mean4 = make_float4(mex, mey, mez, mew);
        float4 sd4 = make_float4(sqrtf(fmaxf(msx - mex * mex, 0.0f) + EPSV),
                                 sqrtf(fmaxf(msy - mey * mey, 0.0f) + EPSV),
                                 sqrtf(fmaxf(msz - mez * mez, 0.0f) + EPSV),
                                 sqrtf(fmaxf(msw - mew * mew, 0.0f) + EPSV));
        bool has = deg > 0;
        float4 mnv4 = has ? make_float4(a4.x + mnx, a4.y + mny, a4.z + mnz, a4.w + mnw)
                          : make_float4(0, 0, 0, 0);
        float4 mxv4 = has ? make_float4(a4.x + mxx, a4.y + mxy, a4.z + mxz, a4.w + mxw)
                          : make_float4(0, 0, 0, 0);
        int j0 = 4 * lane;
        int t = j0 / H, f = j0 - t * H;
        float* bb = base + (size_t)n * BASE_W + t * 160 + f;
        *(float4*)(bb)       = mean4;
        *(float4*)(bb + 40)  = mnv4;
        *(float4*)(bb + 80)  = mxv4;
        *(float4*)(bb + 120) = sd4;
    }
}

// ---------- post einsum, t-split: 2 nodes/thread share LDS weight reads ----------
__global__ __launch_bounds__(256) void k_post(const float* __restrict__ h, const float* __restrict__ base,
                                              const float* __restrict__ amp, const float* __restrict__ att,
                                              const float* __restrict__ post_w, const float* __restrict__ post_b,
                                              float* __restrict__ cpre, int layer) {
    __shared__ float ws[FO * WS_PAD];
    int tid = threadIdx.x;
    int t = blockIdx.y;
    const float* pwsrc = post_w + (size_t)(layer * T + t) * 520 * FO;
    for (int i = tid; i < 520 * FO; i += 256) {
        int g = i >> 3, o = i & 7;
        ws[o * WS_PAD + g] = pwsrc[i];
    }
    __syncthreads();
    int slot = tid >> 3, o = tid & 7;          // slot 0..31 -> node pair
    int n0 = blockIdx.x * 64 + slot * 2;
    if (n0 >= NN) return;
    int n1 = n0 + 1;
    bool two = (n1 < NN);
    if (!two) n1 = n0;
    const float* wrow = ws + o * WS_PAD;
    float am0 = amp[n0], at0 = att[n0];
    float am1 = amp[n1], at1 = att[n1];
    float pb = post_b[(size_t)(layer * T + t) * FO + o];
    float acc0 = pb, acc1 = pb;
    const float4* hx0 = (const float4*)(h + (size_t)n0 * H);
    const float4* hx1 = (const float4*)(h + (size_t)n1 * H);
    #pragma unroll
    for (int g4 = 0; g4 < 10; g4++) {
        float4 wv = *(const float4*)(wrow + g4 * 4);
        float4 x0 = hx0[g4], x1 = hx1[g4];
        acc0 += x0.x * wv.x + x0.y * wv.y + x0.z * wv.z + x0.w * wv.w;
        acc1 += x1.x * wv.x + x1.y * wv.y + x1.z * wv.z + x1.w * wv.w;
    }
    const float4* b0 = (const float4*)(base + (size_t)n0 * BASE_W + t * 160);
    const float4* b1 = (const float4*)(base + (size_t)n1 * BASE_W + t * 160);
    #pragma unroll 8
    for (int g4 = 0; g4 < 40; g4++) {
        float4 wa = *(const float4*)(wrow + 40 + g4 * 4);
        float4 wb = *(const float4*)(wrow + 200 + g4 * 4);
        float4 wc = *(const float4*)(wrow + 360 + g4 * 4);
        float4 v0 = b0[g4], v1 = b1[g4];
        acc0 += v0.x * (wa.x + am0 * wb.x + at0 * wc.x)
              + v0.y * (wa.y + am0 * wb.y + at0 * wc.y)
              + v0.z * (wa.z + am0 * wb.z + at0 * wc.z)
              + v0.w * (wa.w + am0 * wb.w + at0 * wc.w);
        acc1 += v1.x * (wa.x + am1 * wb.x + at1 * wc.x)
              + v1.y * (wa.y + am1 * wb.y + at1 * wc.y)
              + v1.z * (wa.z + am1 * wb.z + at1 * wc.z)
              + v1.w * (wa.w + am1 * wb.w + at1 * wc.w);
    }
    cpre[(size_t)n0 * H + t * FO + o] = acc0;
    if (two) cpre[(size_t)n1 * H + t * FO + o] = acc1;
}

// ---------- fused lin + BN-stats: 6 nodes per block-iter, register accumulation ----------
__global__ __launch_bounds__(256) void k_linbn(const float* __restrict__ cpre, const float* __restrict__ lin_w,
                                               const float* __restrict__ lin_b, float* __restrict__ cbuf,
                                               float* __restrict__ bnsum, float* __restrict__ bnsq, int layer) {
    __shared__ float scp[240];
    __shared__ float red[80];
    int tid = threadIdx.x;
    int j = tid % H, nl = tid / H;      // nl 0..6 (tid 240..255 idle for compute)
    const float* lw = lin_w + (size_t)layer * H * H;
    float wcol[H];
    #pragma unroll
    for (int k = 0; k < H; k++) wcol[k] = lw[k * H + j];
    float lb = lin_b[(size_t)layer * H + j];
    float lsum = 0.0f, lsq = 0.0f;
    for (int n0 = blockIdx.x * 6; n0 < NN; n0 += gridDim.x * 6) {
        int nn = NN - n0; if (nn > 6) nn = 6;
        if (tid < nn * H) scp[tid] = cpre[(size_t)n0 * H + tid];
        __syncthreads();
        if (nl < nn) {
            float acc = lb;
            #pragma unroll
            for (int k = 0; k < H; k++) acc += scp[nl * H + k] * wcol[k];
            cbuf[(size_t)(n0 + nl) * H + j] = acc;
            lsum += acc; lsq += acc * acc;
        }
        __syncthreads();
    }
    if (tid < 80) red[tid] = 0.0f;
    __syncthreads();
    if (nl < 6) { atomicAdd(&red[j], lsum); atomicAdd(&red[40 + j], lsq); }
    __syncthreads();
    if (tid < 40) atomicAdd(&bnsum[tid], red[tid]);
    else if (tid < 80) atomicAdd(&bnsq[tid - 40], red[tid]);
}

// ---------- BN apply + residual ----------
__global__ __launch_bounds__(256) void k_bnapply(const float* __restrict__ cbuf, const float* __restrict__ bnsum,
                                                 const float* __restrict__ bnsq, const float* __restrict__ bn_g,
                                                 const float* __restrict__ bn_b, float* __restrict__ h, int layer) {
    int id = blockIdx.x * 256 + threadIdx.x;
    if (id >= NN * H) return;
    int j = id % H;
    float mu = bnsum[j] / (float)NN;
    float var = bnsq[j] / (float)NN - mu * mu;
    float inv = rsqrtf(var + EPSV);
    float cv = (cbuf[id] - mu) * inv * bn_g[(size_t)layer * H + j] + bn_b[(size_t)layer * H + j];
    h[id] = (h[id] + fmaxf(cv, 0.0f)) * 0.5f;
}

// ---------- final prep: W1e/b1e fold + P1/P2 node partials ----------
__global__ __launch_bounds__(256) void k_prep2(const float* __restrict__ edge_w, const float* __restrict__ edge_b,
                                               const float* __restrict__ w1, const float* __restrict__ b1,
                                               const float* __restrict__ h,
                                               float* __restrict__ W1e, float* __restrict__ b1e,
                                               float* __restrict__ P1, float* __restrict__ P2) {
    int id = blockIdx.x * 256 + threadIdx.x;
    if (id < EFD * 50) {
        int m = id / 50, o = id - m * 50;
        float acc = 0.0f;
        #pragma unroll
        for (int k = 0; k < H; k++) acc += edge_w[m * H + k] * w1[(80 + k) * 50 + o];
        W1e[m * 50 + o] = acc;
        if (m == 0) {
            float bacc = b1[o];
            #pragma unroll
            for (int k = 0; k < H; k++) bacc += edge_b[k] * w1[(80 + k) * 50 + o];
            b1e[o] = bacc;
        }
    } else if (id < EFD * 50 + NN * 50) {
        int id2 = id - EFD * 50;
        int n = id2 / 50, o = id2 - n * 50;
        const float* hr = h + (size_t)n * H;
        float a1 = 0.0f, a2 = 0.0f;
        #pragma unroll
        for (int f = 0; f < H; f++) {
            float v = fmaxf(hr[f], 0.0f);
            a1 += v * w1[f * 50 + o];
            a2 += v * w1[(H + f) * 50 + o];
        }
        P1[(size_t)n * PSTR + o] = a1;
        P2[(size_t)n * PSTR + o] = a2;
    }
}

// ---------- final edge MLP: all weights via uniform scalar loads (no LDS) ----------
__global__ __launch_bounds__(256) void k_mlp(const float* __restrict__ ea_csr, const float* __restrict__ P1,
                                             const float* __restrict__ P2, const float* __restrict__ W1e,
                                             const float* __restrict__ b1e, const float* __restrict__ w2,
                                             const float* __restrict__ b2, const float* __restrict__ w3,
                                             const float* __restrict__ b3, float* __restrict__ out) {
    int p = blockIdx.x * 256 + threadIdx.x;
    if (p >= NE) return;
    const float4* rec = (const float4*)ea_csr + (size_t)p * 4;
    float4 r0 = rec[0], r1 = rec[1], r2 = rec[2], r3 = rec[3];
    int s = __float_as_int(r2.z), d = __float_as_int(r2.w), eid = __float_as_int(r3.x);
    float ea[EFD] = {r0.x, r0.y, r0.z, r0.w, r1.x, r1.y, r1.z, r1.w, r2.x, r2.y};

    float z1[52];
    const float4* p1r = (const float4*)(P1 + (size_t)s * PSTR);
    const float4* p2r = (const float4*)(P2 + (size_t)d * PSTR);
    #pragma unroll
    for (int i = 0; i < 13; i++) {
        float4 a = p1r[i], b = p2r[i];
        z1[4 * i]     = a.x + b.x;
        z1[4 * i + 1] = a.y + b.y;
        z1[4 * i + 2] = a.z + b.z;
        z1[4 * i + 3] = a.w + b.w;
    }
    #pragma unroll
    for (int k = 0; k < 50; k++) z1[k] += b1e[k];              // uniform -> scalar
    #pragma unroll
    for (int m = 0; m < EFD; m++) {
        float v = ea[m];
        #pragma unroll
        for (int k = 0; k < 50; k++) z1[k] = fmaf(v, W1e[m * 50 + k], z1[k]);   // scalar weights
    }
    float z2[25];
    #pragma unroll
    for (int o = 0; o < 25; o++) z2[o] = b2[o];
    #pragma unroll
    for (int k = 0; k < 50; k++) {
        float v = fmaxf(z1[k], 0.0f);
        #pragma unroll
        for (int o = 0; o < 25; o++) z2[o] = fmaf(v, w2[k * 25 + o], z2[o]);    // scalar weights
    }
    float o0 = b3[0], o1 = b3[1];
    #pragma unroll
    for (int k = 0; k < 25; k++) {
        float v = fmaxf(z2[k], 0.0f);
        o0 = fmaf(v, w3[k * 2], o0);
        o1 = fmaf(v, w3[k * 2 + 1], o1);
    }
    *(float2*)(out + (size_t)eid * 2) = make_float2(o0, o1);
}

extern "C" void kernel_launch(void* const* d_in, const int* in_sizes, int n_in,
                              void* d_out, int out_size, void* d_ws, size_t ws_size,
                              hipStream_t stream) {
    const float* x         = (const float*)d_in[0];
    const float* edge_attr = (const float*)d_in[1];
    const int*   eidx      = (const int*)  d_in[2];
    const float* node_w    = (const float*)d_in[3];
    const float* node_b    = (const float*)d_in[4];
    const float* edge_w    = (const float*)d_in[5];
    const float* edge_b    = (const float*)d_in[6];
    const float* enc_w     = (const float*)d_in[7];
    const float* enc_b     = (const float*)d_in[8];
    const float* pre_w     = (const float*)d_in[9];
    const float* pre_b     = (const float*)d_in[10];
    const float* post_w    = (const float*)d_in[11];
    const float* post_b    = (const float*)d_in[12];
    const float* lin_w     = (const float*)d_in[13];
    const float* lin_b     = (const float*)d_in[14];
    const float* bn_g      = (const float*)d_in[15];
    const float* bn_b      = (const float*)d_in[16];
    const float* w1 = (const float*)d_in[17];
    const float* b1 = (const float*)d_in[18];
    const float* w2 = (const float*)d_in[19];
    const float* b2 = (const float*)d_in[20];
    const float* w3 = (const float*)d_in[21];
    const float* b3 = (const float*)d_in[22];
    const int* srcp = eidx;
    const int* dstp = eidx + NE;
    float* out = (float*)d_out;

    char* ws = (char*)d_ws;
    size_t off = 0;
    auto alloc = [&](size_t bytes) -> char* {
        char* p = ws + off;
        off += (bytes + 255) & ~(size_t)255;
        return p;
    };
    float* h      = (float*)alloc((size_t)NN * H * 4);
    float* Abuf   = (float*)alloc((size_t)NN * TF * 4);   // reused as cbuf after k_agg
    __hip_bfloat16* Bbf = (__hip_bfloat16*)alloc((size_t)NN * TF * 2 + 256);
    float* base   = (float*)alloc((size_t)NN * BASE_W * 4);
    float* cpre   = (float*)alloc((size_t)NN * H * 4);
    float* ea_csr = (float*)alloc((size_t)NE * REC * 4);
    float* W3e    = (float*)alloc((size_t)EFD * TF * 4);
    float* dvecF  = (float*)alloc((size_t)TF * 4);
    float* p1T    = (float*)alloc((size_t)TF * H * 4);
    float* p2T    = (float*)alloc((size_t)TF * H * 4);
    float* P1     = (float*)alloc((size_t)NN * PSTR * 4);
    float* P2     = (float*)alloc((size_t)NN * PSTR * 4);
    float* W1e    = (float*)alloc((size_t)EFD * 50 * 4);
    float* b1e    = (float*)alloc((size_t)64 * 4);
    float* amp    = (float*)alloc((size_t)NN * 4);
    float* att    = (float*)alloc((size_t)NN * 4);
    int* offs     = (int*)alloc((size_t)(NN + 1) * 4);
    // ---- contiguous zero region: cnt, fill, avgs, bnz(2 layers) ----
    size_t zoff = off;
    int* cnt_i    = (int*)alloc((size_t)NN * 4);
    int* fill     = (int*)alloc((size_t)NN * 4);
    float* avgs   = (float*)alloc(256);
    float* bnz    = (float*)alloc(1024);   // layer l: bnz + l*128 floats (sum 40 | sq 40)
    size_t zsize = off - zoff;
    if (off > ws_size) return;

    float* cbuf = Abuf;   // safe: A dead after k_agg, cbuf dead before next k_ab

    hipMemsetAsync(cnt_i, 0, zsize, stream);

    k_deg<<<(NE + 255) / 256, 256, 0, stream>>>(dstp, cnt_i);
    k_avglog<<<64, 256, 0, stream>>>(cnt_i, avgs);
    k_node<<<(NN * H + 255) / 256, 256, 0, stream>>>(x, node_w, node_b, h, cnt_i, avgs, amp, att);
    k_scan<<<1, 1024, 0, stream>>>(cnt_i, offs);
    k_scatter<<<(NE + 255) / 256, 256, 0, stream>>>(srcp, dstp, edge_attr, offs, fill, ea_csr);

    for (int layer = 0; layer < LAYERS; layer++) {
        float* bnzL = bnz + layer * 128;
        k_prep1<<<(EFD * TF + TF * H + 255) / 256, 256, 0, stream>>>(
            enc_w, enc_b, edge_w, edge_b, pre_w, pre_b, W3e, dvecF, p1T, p2T, layer);
        k_ab<<<(NN + ABN - 1) / ABN, 256, 0, stream>>>(h, p1T, p2T, Abuf, Bbf);
        k_agg<<<NN / 4, 256, 0, stream>>>(ea_csr, Bbf, Abuf, W3e, dvecF, cnt_i, offs, base);
        k_post<<<dim3((NN + 63) / 64, T), 256, 0, stream>>>(h, base, amp, att, post_w, post_b, cpre, layer);
        k_linbn<<<1024, 256, 0, stream>>>(cpre, lin_w, lin_b, cbuf, bnzL, bnzL + 40, layer);
        k_bnapply<<<(NN * H + 255) / 256, 256, 0, stream>>>(cbuf, bnzL, bnzL + 40, bn_g, bn_b, h, layer);
    }
    k_prep2<<<(EFD * 50 + NN * 50 + 255) / 256, 256, 0, stream>>>(
        edge_w, edge_b, w1, b1, h, W1e, b1e, P1, P2);
    k_mlp<<<(NE + 255) / 256, 256, 0, stream>>>(ea_csr, P1, P2, W1e, b1e, w2, b2, w3, b3, out);
}